// Round 6
// baseline (769.200 us; speedup 1.0000x reference)
//
#include <hip/hip_runtime.h>
#include <hip/hip_bf16.h>
#include <math.h>

#define SS 512
#define HH 768
#define NEGV -1e9f
#define APAD 100

typedef float f32x4 __attribute__((ext_vector_type(4)));
typedef __bf16 bf16x8 __attribute__((ext_vector_type(8)));

__device__ __forceinline__ float telu_f(float x){ return x * tanhf(expf(x)); }

__device__ __forceinline__ short f2bf(float x){
  __hip_bfloat16 h = __float2bfloat16(x);
  return __builtin_bit_cast(short, h);
}
__device__ __forceinline__ float b2f(short s){
  __hip_bfloat16 h = __builtin_bit_cast(__hip_bfloat16, s);
  return __bfloat162float(h);
}

__device__ __forceinline__ void gl_lds16(const void* g, void* l){
  __builtin_amdgcn_global_load_lds((const __attribute__((address_space(1))) void*)g,
                                   (__attribute__((address_space(3))) void*)l, 16, 0, 0);
}

__device__ __forceinline__ float wred_max(float v){
  #pragma unroll
  for (int o=32;o>0;o>>=1) v = fmaxf(v, __shfl_xor(v, o));
  return v;
}
__device__ __forceinline__ float wred_sum(float v){
  #pragma unroll
  for (int o=32;o>0;o>>=1) v += __shfl_xor(v, o);
  return v;
}

// K0: per-batch SEP scan + mask counts + zero atomic accumulators
__global__ __launch_bounds__(512) void k_scan(const int* __restrict__ ids, const int* __restrict__ am,
                       int* s1a, int* s2a, float* invnam, float* invnp, float* invnh,
                       float* __restrict__ uacc, float* __restrict__ v1g, float* __restrict__ v2g){
  int b = blockIdx.x, tid = threadIdx.x;
  __shared__ int mn, mx, cnt;
  if (tid==0){ mn = 1<<30; mx = -1; cnt = 0; }
  __syncthreads();
  int id = ids[b*SS+tid];
  if (id==102){ atomicMin(&mn, tid); atomicMax(&mx, tid); }
  atomicAdd(&cnt, am[b*SS+tid]);
  // zero accumulators (re-poisoned every call)
  #pragma unroll
  for (int i=0;i<4;i++) uacc[(size_t)b*2048 + tid + i*512] = 0.f;
  v1g[b*SS+tid] = 0.f;
  v2g[b*SS+tid] = 0.f;
  __syncthreads();
  if (tid==0){
    int s1 = mn; if (s1 > 255) s1 = 255; if (s1 < 1) s1 = 1;
    int s2 = mx; if (s2 < s1+1) s2 = s1+1; if (s2 > 511) s2 = 511;
    s1a[b]=s1; s2a[b]=s2;
    invnam[b] = 1.f/fmaxf((float)cnt, 1e-9f);
    invnp[b]  = 1.f/fmaxf((float)(s1-1), 1e-9f);
    invnh[b]  = 1.f/fmaxf((float)(s2-s1-1), 1e-9f);
  }
}

// K-g2: fused prep1 (hs->bf16 hi/lo + masked partial reductions) + wt (weight transpose).
// ids [0,768): prep1 ; ids [768,2496): wt
__global__ __launch_bounds__(256) void k_g2(const float* __restrict__ hs, const int* __restrict__ amask,
    const int* __restrict__ s1a, const int* __restrict__ s2a,
    short* __restrict__ hsb, short* __restrict__ hsl, float4* __restrict__ repp,
    const float* __restrict__ wq, const float* __restrict__ wk, const float* __restrict__ wv,
    short* __restrict__ Wt){
  __shared__ __align__(16) char smem[16896];
  int id = blockIdx.x, tid = threadIdx.x;
  if (id < 768){
    int b = id&31, hc = (id>>5)%6, sc = id/192;
    int* ams = (int*)smem;
    float4* rb4 = (float4*)(smem + 512);
    int sbase = sc*128;
    if (tid < 128) ams[tid] = amask[b*SS + sbase + tid];
    __syncthreads();
    int s1 = s1a[b], s2 = s2a[b];
    int hlane = tid & 31, srow = tid >> 5;
    int h0 = hc*128 + hlane*4;
    float sm[4]={0,0,0,0}, sp[4]={0,0,0,0}, sh[4]={0,0,0,0};
    float mxv[4]={NEGV,NEGV,NEGV,NEGV};
    for (int si = srow; si < 128; si += 8){
      int s = sbase + si;
      float4 x = *(const float4*)(hs + ((size_t)(b*SS+s))*HH + h0);
      float xv[4] = {x.x,x.y,x.z,x.w};
      bool am = ams[si] > 0;
      bool ip = (s>=1 && s<s1), ih = (s>s1 && s<s2);
      short hi4[4], lo4[4];
      #pragma unroll
      for (int c=0;c<4;c++){
        if (am){ sm[c]+=xv[c]; mxv[c]=fmaxf(mxv[c],xv[c]); }
        if (ip) sp[c]+=xv[c];
        if (ih) sh[c]+=xv[c];
        hi4[c] = f2bf(xv[c]);
        lo4[c] = f2bf(xv[c] - b2f(hi4[c]));
      }
      *(short4*)(hsb + ((size_t)(b*SS+s))*HH + h0) = *(short4*)hi4;
      *(short4*)(hsl + ((size_t)(b*SS+s))*HH + h0) = *(short4*)lo4;
    }
    #pragma unroll
    for (int c=0;c<4;c++) rb4[srow*128 + hlane*4+c] = make_float4(sm[c], mxv[c], sp[c], sh[c]);
    __syncthreads();
    if (tid < 128){
      float4 a = rb4[tid];
      #pragma unroll
      for (int r=1;r<8;r++){
        float4 v = rb4[r*128 + tid];
        a.x += v.x; a.y = fmaxf(a.y, v.y); a.z += v.z; a.w += v.w;
      }
      repp[(((size_t)(b*6+hc))*4 + sc)*128 + tid] = a;
    }
  } else {
    int w = id - 768;
    int k0 = (w%24)*32, n0 = ((w/24)%24)*32, which = w/576;
    const float* W = which==0? wq : (which==1? wk : wv);
    float (*tl)[33] = (float(*)[33])smem;
    int r = tid>>3, c4 = (tid&7)*4;
    float4 v = *(const float4*)(W + (size_t)(k0+r)*HH + n0 + c4);
    tl[r][c4+0]=v.x; tl[r][c4+1]=v.y; tl[r][c4+2]=v.z; tl[r][c4+3]=v.w;
    __syncthreads();
    short4 o;
    o.x = f2bf(tl[c4+0][r]); o.y = f2bf(tl[c4+1][r]);
    o.z = f2bf(tl[c4+2][r]); o.w = f2bf(tl[c4+3][r]);
    *(short4*)(Wt + (size_t)which*HH*HH + (size_t)(n0+r)*HH + k0 + c4) = o;
  }
}

// K-prep2: combine 4 s-chunk partials -> xfe, sdiff. grid (32,6), block 128.
__global__ __launch_bounds__(128) void k_prep2(const float* __restrict__ hs, const float4* __restrict__ repp,
    const float* __restrict__ invnam, const float* __restrict__ invnp, const float* __restrict__ invnh,
    float* __restrict__ xfe, float* __restrict__ sdiff){
  int b = blockIdx.x, hc = blockIdx.y, tid = threadIdx.x;
  float S=0.f, M=NEGV, P=0.f, Hh=0.f;
  #pragma unroll
  for (int sc=0; sc<4; sc++){
    float4 v = repp[(((size_t)(b*6+hc))*4 + sc)*128 + tid];
    S += v.x; M = fmaxf(M, v.y); P += v.z; Hh += v.w;
  }
  int h = hc*128 + tid;
  float pooled = hs[((size_t)(b*SS))*HH + h];
  xfe[b*HH+h]   = pooled + S*invnam[b] + M;
  sdiff[b*HH+h] = fabsf(P*invnp[b] - Hh*invnh[b]);
}

// K-smallA: ids [0,128): bgemv xfe@fe_w1 -> featd ; ids [128,160): diff tail -> comb[128:256]
__global__ __launch_bounds__(256) void k_smallA(const float* __restrict__ xfe, const float* __restrict__ fe_w1,
    const float* __restrict__ fe_b1, float* __restrict__ featd,
    const float* __restrict__ sdiff, const float* __restrict__ dpw, const float* __restrict__ dpb,
    float* __restrict__ comb){
  __shared__ float xs[HH];
  __shared__ float psum[2][128];
  int id = blockIdx.x, tid = threadIdx.x;
  int jj = tid & 127, half = tid >> 7;
  if (id < 128){
    int b = id&31, j0 = (id>>5)*128;
    for (int i=tid;i<HH;i+=256) xs[i] = xfe[(size_t)b*HH + i];
    __syncthreads();
    float a = 0.f;
    for (int i = half*384; i < half*384+384; i++)
      a += xs[i]*fe_w1[(size_t)i*512 + j0 + jj];
    psum[half][jj] = a;
    __syncthreads();
    if (tid < 128)
      featd[(size_t)b*512 + j0 + tid] = fe_b1[j0+tid] + psum[0][tid] + psum[1][tid];
  } else {
    int b = id - 128;
    for (int i=tid;i<HH;i+=256) xs[i] = sdiff[(size_t)b*HH + i];
    __syncthreads();
    float a = 0.f;
    for (int i = half*384; i < half*384+384; i++)
      a += xs[i]*dpw[(size_t)i*128 + jj];
    psum[half][jj] = a;
    __syncthreads();
    if (tid < 128)
      comb[b*512 + 128 + tid] = telu_f(dpb[tid] + psum[0][tid] + psum[1][tid]);
  }
}

// K-mm: fused qkv GEMM [0,1536) + sim GEMM [1536,2048) + feat2 [2048,2080)
__global__ __launch_bounds__(256) void k_mm(const short* __restrict__ hsb, const short* __restrict__ hsl,
    const short* __restrict__ Wt,
    const float* __restrict__ bq, const float* __restrict__ bk, const float* __restrict__ bv,
    short* __restrict__ qbh, short* __restrict__ kbh, float* __restrict__ vb,
    const int* __restrict__ s1a, const int* __restrict__ s2a, float* __restrict__ sim,
    const float* __restrict__ featd, const float* __restrict__ g, const float* __restrict__ be,
    const float* __restrict__ w2, const float* __restrict__ b2, float* __restrict__ comb){
  __shared__ __align__(16) char smem[32768];
  int id = blockIdx.x;
  int tid = threadIdx.x, lane = tid&63, wave = tid>>6;
  int wm = wave>>1, wn = wave&1;
  int lm = lane&15, lq = lane>>4;
  if (id < 1536){
    // ---- qkv ----
    int which, local;
    if (id < 768){ which=0; local=id; }
    else if (id < 1152){ which=1; local=id-768; }
    else { which=2; local=id-1152; }
    // XCD swizzle: local = (rt%8) + 8*(n + 6*(rt/8))
    int r8 = local & 7, n = (local>>3)%6, gq = local/48;
    int rt = gq*8 + r8;
    int n0 = n*128;
    int r0, b;
    if (which==0){ r0 = rt*128; b = r0>>9; }
    else { b = rt>>1; r0 = b*512 + (rt&1)*128; }
    int s1 = s1a[b], s2 = s2a[b];
    int s0 = r0 & (SS-1);
    if (which==0){ if (s0 >= s2 || s0 + 127 <= s1) return; }
    else { if (s0 >= s1) return; }
    const float* bias = which==0? bq : (which==1? bk : bv);
    const short* Wb = Wt + (size_t)which*HH*HH;
    short* As = (short*)smem;
    short* Bs = As + 4096;
    f32x4 acc[4][4];
    #pragma unroll
    for (int i=0;i<4;i++)
      #pragma unroll
      for (int j=0;j<4;j++) acc[i][j] = (f32x4){0.f,0.f,0.f,0.f};
    for (int k0=0;k0<HH;k0+=32){
      __syncthreads();
      #pragma unroll
      for (int t=0;t<2;t++){
        int c = tid + t*256;
        int ib = c>>6, l = c&63;
        int row = ib*16 + (l&15);
        int kk  = k0 + (l>>4)*8;
        gl_lds16(hsb + (size_t)(r0+row)*HH + kk, As + c*8);
        gl_lds16(Wb  + (size_t)(n0+row)*HH + kk, Bs + c*8);
      }
      __syncthreads();
      bf16x8 af[4], bfv[4];
      #pragma unroll
      for (int i=0;i<4;i++) af[i]  = *(const bf16x8*)&As[((wm*4+i)*64 + lane)*8];
      #pragma unroll
      for (int j=0;j<4;j++) bfv[j] = *(const bf16x8*)&Bs[((wn*4+j)*64 + lane)*8];
      #pragma unroll
      for (int i=0;i<4;i++)
        #pragma unroll
        for (int j=0;j<4;j++)
          acc[i][j] = __builtin_amdgcn_mfma_f32_16x16x32_bf16(af[i], bfv[j], acc[i][j], 0, 0, 0);
    }
    #pragma unroll
    for (int i=0;i<4;i++){
      #pragma unroll
      for (int j=0;j<4;j++){
        int col = n0 + wn*64 + j*16 + lm;
        float bcol = bias[col];
        #pragma unroll
        for (int r4=0;r4<4;r4++){
          int row = r0 + wm*64 + i*16 + lq*4 + r4;
          int s = row & (SS-1);
          float val = acc[i][j][r4] + bcol;
          if (which==0){
            if (s > s1 && s < s2) qbh[(size_t)row*HH + col] = f2bf(val);
          } else if (s >= 1 && s < s1){
            size_t o = ((size_t)(b*256+s))*HH + col;
            if (which==1) kbh[o] = f2bf(val); else vb[o] = val;
          }
        }
      }
    }
  } else if (id < 2048){
    // ---- sim (split-precision) ----
    int local = id - 1536;
    int b = (local&7) + 8*(local>>7);   // XCD swizzle: 16 tiles of batch b on one XCD
    int t = (local>>3)&15;
    int s0 = (t>>2)*128, t0 = (t&3)*128;
    int s2 = s2a[b];
    if (s0 >= s2 || t0 >= s2) return;
    short* Ah = (short*)smem;
    short* Al = Ah + 4096;
    short* Bh = Ah + 8192;
    short* Bl = Ah + 12288;
    const size_t base = (size_t)b*SS*HH;
    f32x4 acc[4][4];
    #pragma unroll
    for (int i=0;i<4;i++)
      #pragma unroll
      for (int j=0;j<4;j++) acc[i][j] = (f32x4){0.f,0.f,0.f,0.f};
    for (int k0=0;k0<HH;k0+=32){
      __syncthreads();
      #pragma unroll
      for (int t2=0;t2<2;t2++){
        int c = tid + t2*256;
        int ib = c>>6, l = c&63;
        int row = ib*16 + (l&15);
        int kk  = k0 + (l>>4)*8;
        gl_lds16(hsb + base + (size_t)(s0+row)*HH + kk, Ah + c*8);
        gl_lds16(hsl + base + (size_t)(s0+row)*HH + kk, Al + c*8);
        gl_lds16(hsb + base + (size_t)(t0+row)*HH + kk, Bh + c*8);
        gl_lds16(hsl + base + (size_t)(t0+row)*HH + kk, Bl + c*8);
      }
      __syncthreads();
      bf16x8 ah[4], al[4], bh[4], bl[4];
      #pragma unroll
      for (int i=0;i<4;i++){
        ah[i] = *(const bf16x8*)&Ah[((wm*4+i)*64 + lane)*8];
        al[i] = *(const bf16x8*)&Al[((wm*4+i)*64 + lane)*8];
      }
      #pragma unroll
      for (int j=0;j<4;j++){
        bh[j] = *(const bf16x8*)&Bh[((wn*4+j)*64 + lane)*8];
        bl[j] = *(const bf16x8*)&Bl[((wn*4+j)*64 + lane)*8];
      }
      #pragma unroll
      for (int i=0;i<4;i++)
        #pragma unroll
        for (int j=0;j<4;j++){
          acc[i][j] = __builtin_amdgcn_mfma_f32_16x16x32_bf16(ah[i], bh[j], acc[i][j], 0, 0, 0);
          acc[i][j] = __builtin_amdgcn_mfma_f32_16x16x32_bf16(ah[i], bl[j], acc[i][j], 0, 0, 0);
          acc[i][j] = __builtin_amdgcn_mfma_f32_16x16x32_bf16(al[i], bh[j], acc[i][j], 0, 0, 0);
        }
    }
    #pragma unroll
    for (int i=0;i<4;i++){
      #pragma unroll
      for (int j=0;j<4;j++){
        int col = t0 + wn*64 + j*16 + lm;
        #pragma unroll
        for (int r4=0;r4<4;r4++){
          int row = s0 + wm*64 + i*16 + lq*4 + r4;
          sim[((size_t)(b*SS+row))*SS + col] = acc[i][j][r4];
        }
      }
    }
  } else {
    // ---- feat2: LN + 512->128 + telu ----
    int b = id - 2048;
    float* hv  = (float*)smem;
    float* hn  = hv + 512;
    float* red = hn + 512;
    float* ps  = red + 256;     // [2][128]
    hv[tid] = featd[(size_t)b*512 + tid];
    hv[tid+256] = featd[(size_t)b*512 + tid + 256];
    __syncthreads();
    red[tid] = hv[tid] + hv[tid+256];
    __syncthreads();
    for (int st=128; st>0; st>>=1){ if (tid<st) red[tid]+=red[tid+st]; __syncthreads(); }
    float mean = red[0]*(1.f/512.f);
    __syncthreads();
    float d0 = hv[tid]-mean, d1 = hv[tid+256]-mean;
    red[tid] = d0*d0 + d1*d1;
    __syncthreads();
    for (int st=128; st>0; st>>=1){ if (tid<st) red[tid]+=red[tid+st]; __syncthreads(); }
    float inv = 1.f/sqrtf(red[0]*(1.f/512.f) + 1e-5f);
    __syncthreads();
    hn[tid]     = d0*inv*g[tid]     + be[tid];
    hn[tid+256] = d1*inv*g[tid+256] + be[tid+256];
    __syncthreads();
    int jj = tid & 127, half = tid >> 7;
    float a = 0.f;
    for (int k = half*256; k < half*256+256; k++)
      a += hn[k]*w2[k*128 + jj];
    ps[half*128 + jj] = a;
    __syncthreads();
    if (tid < 128)
      comb[b*512 + tid] = telu_f(b2[tid] + ps[tid] + ps[128+tid]);
  }
}

// K-as: fused attention [0,2048) + simsm [2048,2304)
__global__ __launch_bounds__(256) void k_attn_simsm(const short* __restrict__ qbh, const short* __restrict__ kbh,
    const int* __restrict__ s1a, const int* __restrict__ s2a, float* __restrict__ uacc,
    const float* __restrict__ sim, float* __restrict__ v1g, float* __restrict__ v2g){
  __shared__ __align__(16) char smem[64000];
  int id = blockIdx.x, tid = threadIdx.x;
  int wave = tid>>6, lane = tid&63;
  if (id < 2048){
    int b = id&31, h = (id>>5)&7, zc = id>>8;
    int s1 = s1a[b], s2 = s2a[b];
    int qs = s1 + 1 + zc*64;
    if (qs >= s2) return;
    short* Ks = (short*)smem;
    short* Qs = Ks + 256*APAD;
    int lm = lane&15, lq = lane>>4;
    int jmax = (s1+15)>>4;
    int krows = jmax<<4;
    for (int i = tid; i < krows*12; i += 256){
      int r = i/12, c = i - r*12;
      *(int4*)&Ks[r*APAD + c*8] = *(const int4*)(kbh + ((size_t)(b*256+r))*HH + h*96 + c*8);
    }
    for (int i = tid; i < 64*12; i += 256){
      int r = i/12, c = i - r*12;
      int q = qs + r;
      int4 v = {0,0,0,0};
      if (q < SS) v = *(const int4*)(qbh + ((size_t)(b*SS+q))*HH + h*96 + c*8);
      *(int4*)&Qs[r*APAD + c*8] = v;
    }
    __syncthreads();
    f32x4 acc[16];
    #pragma unroll
    for (int j=0;j<16;j++) acc[j] = (f32x4){0.f,0.f,0.f,0.f};
    #pragma unroll
    for (int ks=0; ks<3; ks++){
      bf16x8 a = *(const bf16x8*)&Qs[(wave*16+lm)*APAD + ks*32 + lq*8];
      #pragma unroll
      for (int j=0;j<16;j++){
        if (j < jmax){
          bf16x8 bfr = *(const bf16x8*)&Ks[(j*16+lm)*APAD + ks*32 + lq*8];
          acc[j] = __builtin_amdgcn_mfma_f32_16x16x32_bf16(a, bfr, acc[j], 0, 0, 0);
        }
      }
    }
    const float scale = 0.1020620726f;
    float uj[16];
    #pragma unroll
    for (int j=0;j<16;j++) uj[j]=0.f;
    int qrow_base = qs + wave*16 + lq*4;
    #pragma unroll
    for (int r=0;r<4;r++){
      float m = -1e30f;
      float sc[16];
      #pragma unroll
      for (int j=0;j<16;j++){
        int c = j*16 + lm;
        float s = (c>=1 && c<s1) ? acc[j][r]*scale : -1e30f;
        sc[j] = s; m = fmaxf(m, s);
      }
      #pragma unroll
      for (int o=1;o<16;o<<=1) m = fmaxf(m, __shfl_xor(m, o));
      float ssum = 0.f;
      #pragma unroll
      for (int j=0;j<16;j++){ float p = expf(sc[j]-m); sc[j]=p; ssum += p; }
      #pragma unroll
      for (int o=1;o<16;o<<=1) ssum += __shfl_xor(ssum, o);
      bool rvalid = (qrow_base + r) < s2;
      float inv = rvalid ? 1.f/ssum : 0.f;
      #pragma unroll
      for (int j=0;j<16;j++) uj[j] += sc[j]*inv;
    }
    #pragma unroll
    for (int j=0;j<16;j++){
      if (j < jmax){
        float v = uj[j];
        v += __shfl_xor(v, 16);
        v += __shfl_xor(v, 32);
        if (lq==0 && v != 0.f)
          atomicAdd(&uacc[((size_t)(b*8+h))*256 + j*16 + lm], v);
      }
    }
  } else {
    int l = id - 2048;
    int b = l&31, cy = l>>5;
    int s1 = s1a[b], s2 = s2a[b];
    int r0 = cy*64;
    float* av = (float*)smem;   // [2][4][SS]
    for (int i=tid;i<2*4*SS;i+=256) av[i]=0.f;
    __syncthreads();
    for (int r = r0 + wave; r < r0+64; r += 4){
      int t0,t1,which;
      if (r>=1 && r<s1){ t0=s1+1; t1=s2; which=0; }
      else if (r>s1 && r<s2){ t0=1; t1=s1; which=1; }
      else continue;
      const float* row = sim + ((size_t)(b*SS+r))*SS;
      float vals[7]; float mx=-1e30f;
      #pragma unroll
      for (int j=0;j<7;j++){
        int t = t0 + lane + 64*j;
        vals[j] = (t<t1) ? row[t] : -1e30f;
        mx = fmaxf(mx, vals[j]);
      }
      mx = wred_max(mx);
      float ssum=0.f;
      #pragma unroll
      for (int j=0;j<7;j++){
        int t = t0+lane+64*j;
        vals[j] = (t<t1)? expf(vals[j]-mx) : 0.f;
        ssum += vals[j];
      }
      ssum = wred_sum(ssum);
      float inv = 1.f/ssum;
      #pragma unroll
      for (int j=0;j<7;j++){
        int t = t0+lane+64*j;
        if (t<t1) av[(which*4 + wave)*SS + t] += vals[j]*inv;
      }
    }
    __syncthreads();
    for (int t=tid;t<SS;t+=256){
      float a0 = av[0*SS+t]+av[1*SS+t]+av[2*SS+t]+av[3*SS+t];
      float a1 = av[4*SS+t]+av[5*SS+t]+av[6*SS+t]+av[7*SS+t];
      if (a0 != 0.f) atomicAdd(&v1g[b*SS+t], a0);
      if (a1 != 0.f) atomicAdd(&v2g[b*SS+t], a1);
    }
  }
}

// K-ca: fused ctx [0,192) + alvec [192,576)
__global__ __launch_bounds__(256) void k_ctx_alvec(const float* __restrict__ uacc, const float* __restrict__ vb,
    const int* __restrict__ s1a, const float* __restrict__ invnh, float* __restrict__ cmg,
    const float* __restrict__ hs, const float* __restrict__ v1g, const float* __restrict__ v2g,
    const float* __restrict__ invnp, float* __restrict__ catg){
  __shared__ __align__(16) char smem[9216];
  int id = blockIdx.x, tid = threadIdx.x;
  if (id < 192){
    int b = id&31, i0 = (id>>5)*128;
    int s1 = s1a[b]; int nk = s1-1;
    float inh = invnh[b];
    float* us = (float*)smem;           // 2048
    float* ps = us + 2048;              // [2][128]
    for (int idx=tid; idx<2048; idx+=256) us[idx] = uacc[(size_t)b*2048 + idx];
    __syncthreads();
    int ii = tid & 127, half = tid >> 7;
    int i = i0 + ii;
    int h = i/96;
    float a = 0.f;
    int lo = 1 + half*128;
    int hi = nk < (lo+127) ? nk : (lo+127);
    for (int sl=lo; sl<=hi; sl++)
      a += us[h*256+sl]*vb[((size_t)(b*256+sl))*HH + i];
    ps[half*128 + ii] = a;
    __syncthreads();
    if (tid < 128)
      cmg[(size_t)b*HH + i0 + tid] = (ps[tid] + ps[128+tid])*inh;
  } else {
    int l = id - 192;
    int b = l&31, d0 = (l>>5)*64;
    float* sv1 = (float*)smem;          // 512
    float* sv2 = sv1 + 512;             // 512
    float* p1  = sv2 + 512;             // [4][64]
    float* p2  = p1 + 256;              // [4][64]
    for (int t=tid;t<SS;t+=256){ sv1[t]=v1g[b*SS+t]; sv2[t]=v2g[b*SS+t]; }
    __syncthreads();
    int d = d0 + (tid&63), ch = tid>>6;
    float a1=0.f, a2=0.f;
    for (int t=ch*128; t<ch*128+128; t++){
      float x = hs[((size_t)(b*SS+t))*HH + d];
      a1 += sv1[t]*x; a2 += sv2[t]*x;
    }
    p1[ch*64 + (tid&63)]=a1; p2[ch*64 + (tid&63)]=a2;
    __syncthreads();
    if (tid < 64){
      float s1_ = p1[tid]+p1[64+tid]+p1[128+tid]+p1[192+tid];
      float s2_ = p2[tid]+p2[64+tid]+p2[128+tid]+p2[192+tid];
      catg[(size_t)b*1536 + d0 + tid]       = s1_*invnp[b];
      catg[(size_t)b*1536 + 768 + d0 + tid] = s2_*invnh[b];
    }
  }
}

// K-gB: fused wo-gemv [0,192) + al_w1-gemv [192,384); N=768 both
__global__ __launch_bounds__(256) void k_gemvB(const float* __restrict__ cmg, const float* __restrict__ wo,
    const float* __restrict__ bo, float* __restrict__ accg,
    const float* __restrict__ catg, const float* __restrict__ al_w1, const float* __restrict__ al_b1,
    float* __restrict__ tmpg){
  __shared__ float xs[1536];
  __shared__ float psum[2][128];
  int id = blockIdx.x, tid = threadIdx.x;
  const float *x, *W, *bias; float* y; int K, b, j0;
  if (id < 192){ b = id&31; j0 = (id>>5)*128; x=cmg;  W=wo;    bias=bo;    y=accg; K=768; }
  else { int l=id-192; b = l&31; j0 = (l>>5)*128; x=catg; W=al_w1; bias=al_b1; y=tmpg; K=1536; }
  for (int i=tid;i<K;i+=256) xs[i] = x[(size_t)b*K + i];
  __syncthreads();
  int jj = tid & 127, half = tid >> 7;
  int j = j0 + jj;
  float a = 0.f;
  int Kh = K>>1;
  for (int i = half*Kh; i < (half+1)*Kh; i++)
    a += xs[i]*W[(size_t)i*HH + j];
  psum[half][jj] = a;
  __syncthreads();
  if (tid < 128)
    y[(size_t)b*HH + j0 + tid] = bias[j0+tid] + psum[0][tid] + psum[1][tid];
}

// K-tC: fused ap tail [0,32) + al tail [32,64) -> comb
__global__ __launch_bounds__(256) void k_tailsC(const float* __restrict__ accg, const float* __restrict__ apw,
    const float* __restrict__ apb, const float* __restrict__ tmpg, const float* __restrict__ al_w2,
    const float* __restrict__ al_b2, float* __restrict__ comb){
  __shared__ float xs[HH];
  __shared__ float psum[2][128];
  int id = blockIdx.x, tid = threadIdx.x;
  const float *x, *W, *bias; int b, off;
  if (id < 32){ b = id; x=accg; W=apw; bias=apb; off=256; }
  else { b = id-32; x=tmpg; W=al_w2; bias=al_b2; off=384; }
  for (int i=tid;i<HH;i+=256) xs[i] = x[(size_t)b*HH + i];
  __syncthreads();
  int jj = tid & 127, half = tid >> 7;
  float a = 0.f;
  for (int i = half*384; i < half*384+384; i++)
    a += xs[i]*W[(size_t)i*128 + jj];
  psum[half][jj] = a;
  __syncthreads();
  if (tid < 128)
    comb[b*512 + off + tid] = telu_f(bias[tid] + psum[0][tid] + psum[1][tid]);
}

// K10: classifier head
__global__ __launch_bounds__(64) void k_cls(const float* __restrict__ comb,
    const float* __restrict__ w1, const float* __restrict__ b1,
    const float* __restrict__ w2, const float* __restrict__ b2, float* __restrict__ out){
  int b=blockIdx.x, tid=threadIdx.x;
  __shared__ float cb[512];
  __shared__ float t1[64];
  for (int i=tid;i<512;i+=64) cb[i]=comb[b*512+i];
  __syncthreads();
  float a = b1[tid];
  for (int k=0;k<512;k++) a += cb[k]*w1[(size_t)k*64+tid];
  t1[tid]=telu_f(a);
  __syncthreads();
  if (tid<3){
    float o = b2[tid];
    for (int k=0;k<64;k++) o += t1[k]*w2[k*3+tid];
    out[b*3+tid]=o;
  }
}

extern "C" void kernel_launch(void* const* d_in, const int* in_sizes, int n_in,
                              void* d_out, int out_size, void* d_ws, size_t ws_size,
                              hipStream_t stream){
  const float* hs   = (const float*)d_in[0];
  const int*   ids  = (const int*)d_in[1];
  const int*   amask= (const int*)d_in[2];
  const float* fe_w1= (const float*)d_in[3];
  const float* fe_b1= (const float*)d_in[4];
  const float* fe_g = (const float*)d_in[5];
  const float* fe_be= (const float*)d_in[6];
  const float* fe_w2= (const float*)d_in[7];
  const float* fe_b2= (const float*)d_in[8];
  const float* al_w1= (const float*)d_in[9];
  const float* al_b1= (const float*)d_in[10];
  const float* al_w2= (const float*)d_in[11];
  const float* al_b2= (const float*)d_in[12];
  const float* wq   = (const float*)d_in[13];
  const float* bq   = (const float*)d_in[14];
  const float* wk   = (const float*)d_in[15];
  const float* bk   = (const float*)d_in[16];
  const float* wv   = (const float*)d_in[17];
  const float* bv   = (const float*)d_in[18];
  const float* wo   = (const float*)d_in[19];
  const float* bo   = (const float*)d_in[20];
  const float* dpw  = (const float*)d_in[21];
  const float* dpb  = (const float*)d_in[22];
  const float* apw  = (const float*)d_in[23];
  const float* apb  = (const float*)d_in[24];
  const float* clw1 = (const float*)d_in[25];
  const float* clb1 = (const float*)d_in[26];
  const float* clw2 = (const float*)d_in[27];
  const float* clb2 = (const float*)d_in[28];
  float* out = (float*)d_out;

  char* base = (char*)d_ws;
  size_t off = 0;
  auto alloc = [&](size_t bytes)->char*{ char* p = base + off; off += (bytes + 255) & ~(size_t)255; return p; };
  short* hsb  = (short*)alloc((size_t)32*SS*HH*2);
  short* hsl  = (short*)alloc((size_t)32*SS*HH*2);
  short* Wt   = (short*)alloc((size_t)3*HH*HH*2);
  short* qbh  = (short*)alloc((size_t)32*SS*HH*2);
  short* kbh  = (short*)alloc((size_t)32*256*HH*2);
  float* vb   = (float*)alloc((size_t)32*256*HH*4);
  float* simb = (float*)alloc((size_t)32*SS*SS*4);
  float* uacc = (float*)alloc((size_t)32*8*256*4);
  float* v1g  = (float*)alloc((size_t)32*SS*4);
  float* v2g  = (float*)alloc((size_t)32*SS*4);
  int*   s1a  = (int*)alloc(32*4);
  int*   s2a  = (int*)alloc(32*4);
  float* invnam=(float*)alloc(32*4);
  float* invnp =(float*)alloc(32*4);
  float* invnh =(float*)alloc(32*4);
  float* xfe  = (float*)alloc((size_t)32*HH*4);
  float* sdiff= (float*)alloc((size_t)32*HH*4);
  float* comb = (float*)alloc((size_t)32*512*4);
  float4* repp= (float4*)alloc((size_t)32*6*4*128*16);
  float* featd= (float*)alloc((size_t)32*512*4);
  float* catg = (float*)alloc((size_t)32*1536*4);
  float* tmpg = (float*)alloc((size_t)32*HH*4);
  float* cmg  = (float*)alloc((size_t)32*HH*4);
  float* accg = (float*)alloc((size_t)32*HH*4);

  k_scan<<<dim3(32), dim3(512), 0, stream>>>(ids, amask, s1a, s2a, invnam, invnp, invnh, uacc, v1g, v2g);
  k_g2<<<dim3(2496), dim3(256), 0, stream>>>(hs, amask, s1a, s2a, hsb, hsl, repp, wq, wk, wv, Wt);
  k_prep2<<<dim3(32,6), dim3(128), 0, stream>>>(hs, repp, invnam, invnp, invnh, xfe, sdiff);
  k_smallA<<<dim3(160), dim3(256), 0, stream>>>(xfe, fe_w1, fe_b1, featd, sdiff, dpw, dpb, comb);
  k_mm<<<dim3(2080), dim3(256), 0, stream>>>(hsb, hsl, Wt, bq, bk, bv, qbh, kbh, vb, s1a, s2a, simb,
                                             featd, fe_g, fe_be, fe_w2, fe_b2, comb);
  k_attn_simsm<<<dim3(2304), dim3(256), 0, stream>>>(qbh, kbh, s1a, s2a, uacc, simb, v1g, v2g);
  k_ctx_alvec<<<dim3(576), dim3(256), 0, stream>>>(uacc, vb, s1a, invnh, cmg, hs, v1g, v2g, invnp, catg);
  k_gemvB<<<dim3(384), dim3(256), 0, stream>>>(cmg, wo, bo, accg, catg, al_w1, al_b1, tmpg);
  k_tailsC<<<dim3(64), dim3(256), 0, stream>>>(accg, apw, apb, tmpg, al_w2, al_b2, comb);
  k_cls<<<dim3(32), dim3(64), 0, stream>>>(comb, clw1, clb1, clw2, clb2, out);
}

// Round 7
// 544.385 us; speedup vs baseline: 1.4130x; 1.4130x over previous
//
#include <hip/hip_runtime.h>
#include <hip/hip_bf16.h>
#include <math.h>

#define SS 512
#define HH 768
#define NEGV -1e9f
#define APAD 100

typedef float f32x4 __attribute__((ext_vector_type(4)));
typedef __bf16 bf16x8 __attribute__((ext_vector_type(8)));

__device__ __forceinline__ float telu_f(float x){ return x * tanhf(expf(x)); }

__device__ __forceinline__ short f2bf(float x){
  __hip_bfloat16 h = __float2bfloat16(x);
  return __builtin_bit_cast(short, h);
}
__device__ __forceinline__ float b2f(short s){
  __hip_bfloat16 h = __builtin_bit_cast(__hip_bfloat16, s);
  return __bfloat162float(h);
}

__device__ __forceinline__ void gl_lds16(const void* g, void* l){
  __builtin_amdgcn_global_load_lds((const __attribute__((address_space(1))) void*)g,
                                   (__attribute__((address_space(3))) void*)l, 16, 0, 0);
}

__device__ __forceinline__ float wred_max(float v){
  #pragma unroll
  for (int o=32;o>0;o>>=1) v = fmaxf(v, __shfl_xor(v, o));
  return v;
}
__device__ __forceinline__ float wred_sum(float v){
  #pragma unroll
  for (int o=32;o>0;o>>=1) v += __shfl_xor(v, o);
  return v;
}

// K0: per-batch SEP scan + mask counts + zero atomic accumulators
__global__ __launch_bounds__(512) void k_scan(const int* __restrict__ ids, const int* __restrict__ am,
                       int* s1a, int* s2a, float* invnam, float* invnp, float* invnh,
                       float* __restrict__ uacc, float* __restrict__ v1g, float* __restrict__ v2g){
  int b = blockIdx.x, tid = threadIdx.x;
  __shared__ int mn, mx, cnt;
  if (tid==0){ mn = 1<<30; mx = -1; cnt = 0; }
  __syncthreads();
  int id = ids[b*SS+tid];
  if (id==102){ atomicMin(&mn, tid); atomicMax(&mx, tid); }
  atomicAdd(&cnt, am[b*SS+tid]);
  #pragma unroll
  for (int i=0;i<4;i++) uacc[(size_t)b*2048 + tid + i*512] = 0.f;
  v1g[b*SS+tid] = 0.f;
  v2g[b*SS+tid] = 0.f;
  __syncthreads();
  if (tid==0){
    int s1 = mn; if (s1 > 255) s1 = 255; if (s1 < 1) s1 = 1;
    int s2 = mx; if (s2 < s1+1) s2 = s1+1; if (s2 > 511) s2 = 511;
    s1a[b]=s1; s2a[b]=s2;
    invnam[b] = 1.f/fmaxf((float)cnt, 1e-9f);
    invnp[b]  = 1.f/fmaxf((float)(s1-1), 1e-9f);
    invnh[b]  = 1.f/fmaxf((float)(s2-s1-1), 1e-9f);
  }
}

// K-g2: fused prep1 (hs->bf16 hi/lo + masked partial reductions) + wt (weight transpose).
__global__ __launch_bounds__(256) void k_g2(const float* __restrict__ hs, const int* __restrict__ amask,
    const int* __restrict__ s1a, const int* __restrict__ s2a,
    short* __restrict__ hsb, short* __restrict__ hsl, float4* __restrict__ repp,
    const float* __restrict__ wq, const float* __restrict__ wk, const float* __restrict__ wv,
    short* __restrict__ Wt){
  __shared__ __align__(16) char smem[16896];
  int id = blockIdx.x, tid = threadIdx.x;
  if (id < 768){
    int b = id&31, hc = (id>>5)%6, sc = id/192;
    int* ams = (int*)smem;
    float4* rb4 = (float4*)(smem + 512);
    int sbase = sc*128;
    if (tid < 128) ams[tid] = amask[b*SS + sbase + tid];
    __syncthreads();
    int s1 = s1a[b], s2 = s2a[b];
    int hlane = tid & 31, srow = tid >> 5;
    int h0 = hc*128 + hlane*4;
    float sm[4]={0,0,0,0}, sp[4]={0,0,0,0}, sh[4]={0,0,0,0};
    float mxv[4]={NEGV,NEGV,NEGV,NEGV};
    for (int si = srow; si < 128; si += 8){
      int s = sbase + si;
      float4 x = *(const float4*)(hs + ((size_t)(b*SS+s))*HH + h0);
      float xv[4] = {x.x,x.y,x.z,x.w};
      bool am = ams[si] > 0;
      bool ip = (s>=1 && s<s1), ih = (s>s1 && s<s2);
      short hi4[4], lo4[4];
      #pragma unroll
      for (int c=0;c<4;c++){
        if (am){ sm[c]+=xv[c]; mxv[c]=fmaxf(mxv[c],xv[c]); }
        if (ip) sp[c]+=xv[c];
        if (ih) sh[c]+=xv[c];
        hi4[c] = f2bf(xv[c]);
        lo4[c] = f2bf(xv[c] - b2f(hi4[c]));
      }
      *(short4*)(hsb + ((size_t)(b*SS+s))*HH + h0) = *(short4*)hi4;
      *(short4*)(hsl + ((size_t)(b*SS+s))*HH + h0) = *(short4*)lo4;
    }
    #pragma unroll
    for (int c=0;c<4;c++) rb4[srow*128 + hlane*4+c] = make_float4(sm[c], mxv[c], sp[c], sh[c]);
    __syncthreads();
    if (tid < 128){
      float4 a = rb4[tid];
      #pragma unroll
      for (int r=1;r<8;r++){
        float4 v = rb4[r*128 + tid];
        a.x += v.x; a.y = fmaxf(a.y, v.y); a.z += v.z; a.w += v.w;
      }
      repp[(((size_t)(b*6+hc))*4 + sc)*128 + tid] = a;
    }
  } else {
    int w = id - 768;
    int k0 = (w%24)*32, n0 = ((w/24)%24)*32, which = w/576;
    const float* W = which==0? wq : (which==1? wk : wv);
    float (*tl)[33] = (float(*)[33])smem;
    int r = tid>>3, c4 = (tid&7)*4;
    float4 v = *(const float4*)(W + (size_t)(k0+r)*HH + n0 + c4);
    tl[r][c4+0]=v.x; tl[r][c4+1]=v.y; tl[r][c4+2]=v.z; tl[r][c4+3]=v.w;
    __syncthreads();
    short4 o;
    o.x = f2bf(tl[c4+0][r]); o.y = f2bf(tl[c4+1][r]);
    o.z = f2bf(tl[c4+2][r]); o.w = f2bf(tl[c4+3][r]);
    *(short4*)(Wt + (size_t)which*HH*HH + (size_t)(n0+r)*HH + k0 + c4) = o;
  }
}

// helper: reconstruct xfe[b][h] or sdiff[b][h] into xs[0..767] from repp partials
__device__ __forceinline__ void build_vec(const float4* __restrict__ repp, const float* __restrict__ hs,
    const float* __restrict__ invnam, const float* __restrict__ invnp, const float* __restrict__ invnh,
    int b, int tid, bool want_sdiff, float* xs){
  for (int h = tid; h < HH; h += 256){
    int hc = h>>7, hr = h&127;
    float S=0.f, M=NEGV, P=0.f, Hh=0.f;
    #pragma unroll
    for (int sc=0; sc<4; sc++){
      float4 v = repp[(((size_t)(b*6+hc))*4 + sc)*128 + hr];
      S += v.x; M = fmaxf(M, v.y); P += v.z; Hh += v.w;
    }
    if (want_sdiff) xs[h] = fabsf(P*invnp[b] - Hh*invnh[b]);
    else            xs[h] = hs[((size_t)(b*SS))*HH + h] + S*invnam[b] + M;
  }
}

// K-smallA: ids [0,128): gemv xfe@fe_w1 -> featd ; ids [128,160): diff tail -> comb[128:256]
__global__ __launch_bounds__(256) void k_smallA(const float4* __restrict__ repp, const float* __restrict__ hs,
    const float* __restrict__ invnam, const float* __restrict__ invnp, const float* __restrict__ invnh,
    const float* __restrict__ fe_w1, const float* __restrict__ fe_b1, float* __restrict__ featd,
    const float* __restrict__ dpw, const float* __restrict__ dpb, float* __restrict__ comb){
  __shared__ float xs[HH];
  __shared__ float psum[2][128];
  int id = blockIdx.x, tid = threadIdx.x;
  int jj = tid & 127, half = tid >> 7;
  if (id < 128){
    int b = id&31, j0 = (id>>5)*128;
    build_vec(repp, hs, invnam, invnp, invnh, b, tid, false, xs);
    __syncthreads();
    float a = 0.f;
    #pragma unroll 8
    for (int i = half*384; i < half*384+384; i++)
      a += xs[i]*fe_w1[(size_t)i*512 + j0 + jj];
    psum[half][jj] = a;
    __syncthreads();
    if (tid < 128)
      featd[(size_t)b*512 + j0 + tid] = fe_b1[j0+tid] + psum[0][tid] + psum[1][tid];
  } else {
    int b = id - 128;
    build_vec(repp, hs, invnam, invnp, invnh, b, tid, true, xs);
    __syncthreads();
    float a = 0.f;
    #pragma unroll 8
    for (int i = half*384; i < half*384+384; i++)
      a += xs[i]*dpw[(size_t)i*128 + jj];
    psum[half][jj] = a;
    __syncthreads();
    if (tid < 128)
      comb[b*512 + 128 + tid] = telu_f(dpb[tid] + psum[0][tid] + psum[1][tid]);
  }
}

// K-mm: fused qkv GEMM [0,1536) + sim GEMM [1536,2048)
__global__ __launch_bounds__(256) void k_mm(const short* __restrict__ hsb, const short* __restrict__ hsl,
    const short* __restrict__ Wt,
    const float* __restrict__ bq, const float* __restrict__ bk, const float* __restrict__ bv,
    short* __restrict__ qbh, short* __restrict__ kbh, float* __restrict__ vb,
    const int* __restrict__ s1a, const int* __restrict__ s2a, float* __restrict__ sim){
  __shared__ __align__(16) char smem[32768];
  int id = blockIdx.x;
  int tid = threadIdx.x, lane = tid&63, wave = tid>>6;
  int wm = wave>>1, wn = wave&1;
  int lm = lane&15, lq = lane>>4;
  if (id < 1536){
    int which, local;
    if (id < 768){ which=0; local=id; }
    else if (id < 1152){ which=1; local=id-768; }
    else { which=2; local=id-1152; }
    int r8 = local & 7, n = (local>>3)%6, gq = local/48;
    int rt = gq*8 + r8;
    int n0 = n*128;
    int r0, b;
    if (which==0){ r0 = rt*128; b = r0>>9; }
    else { b = rt>>1; r0 = b*512 + (rt&1)*128; }
    int s1 = s1a[b], s2 = s2a[b];
    int s0 = r0 & (SS-1);
    if (which==0){ if (s0 >= s2 || s0 + 127 <= s1) return; }
    else { if (s0 >= s1) return; }
    const float* bias = which==0? bq : (which==1? bk : bv);
    const short* Wb = Wt + (size_t)which*HH*HH;
    short* As = (short*)smem;
    short* Bs = As + 4096;
    f32x4 acc[4][4];
    #pragma unroll
    for (int i=0;i<4;i++)
      #pragma unroll
      for (int j=0;j<4;j++) acc[i][j] = (f32x4){0.f,0.f,0.f,0.f};
    for (int k0=0;k0<HH;k0+=32){
      __syncthreads();
      #pragma unroll
      for (int t=0;t<2;t++){
        int c = tid + t*256;
        int ib = c>>6, l = c&63;
        int row = ib*16 + (l&15);
        int kk  = k0 + (l>>4)*8;
        gl_lds16(hsb + (size_t)(r0+row)*HH + kk, As + c*8);
        gl_lds16(Wb  + (size_t)(n0+row)*HH + kk, Bs + c*8);
      }
      __syncthreads();
      bf16x8 af[4], bfv[4];
      #pragma unroll
      for (int i=0;i<4;i++) af[i]  = *(const bf16x8*)&As[((wm*4+i)*64 + lane)*8];
      #pragma unroll
      for (int j=0;j<4;j++) bfv[j] = *(const bf16x8*)&Bs[((wn*4+j)*64 + lane)*8];
      #pragma unroll
      for (int i=0;i<4;i++)
        #pragma unroll
        for (int j=0;j<4;j++)
          acc[i][j] = __builtin_amdgcn_mfma_f32_16x16x32_bf16(af[i], bfv[j], acc[i][j], 0, 0, 0);
    }
    #pragma unroll
    for (int i=0;i<4;i++){
      #pragma unroll
      for (int j=0;j<4;j++){
        int col = n0 + wn*64 + j*16 + lm;
        float bcol = bias[col];
        #pragma unroll
        for (int r4=0;r4<4;r4++){
          int row = r0 + wm*64 + i*16 + lq*4 + r4;
          int s = row & (SS-1);
          float val = acc[i][j][r4] + bcol;
          if (which==0){
            if (s > s1 && s < s2) qbh[(size_t)row*HH + col] = f2bf(val);
          } else if (s >= 1 && s < s1){
            size_t o = ((size_t)(b*256+s))*HH + col;
            if (which==1) kbh[o] = f2bf(val); else vb[o] = val;
          }
        }
      }
    }
  } else {
    int local = id - 1536;
    int b = (local&7) + 8*(local>>7);
    int t = (local>>3)&15;
    int s0 = (t>>2)*128, t0 = (t&3)*128;
    int s2 = s2a[b];
    if (s0 >= s2 || t0 >= s2) return;
    short* Ah = (short*)smem;
    short* Al = Ah + 4096;
    short* Bh = Ah + 8192;
    short* Bl = Ah + 12288;
    const size_t base = (size_t)b*SS*HH;
    f32x4 acc[4][4];
    #pragma unroll
    for (int i=0;i<4;i++)
      #pragma unroll
      for (int j=0;j<4;j++) acc[i][j] = (f32x4){0.f,0.f,0.f,0.f};
    for (int k0=0;k0<HH;k0+=32){
      __syncthreads();
      #pragma unroll
      for (int t2=0;t2<2;t2++){
        int c = tid + t2*256;
        int ib = c>>6, l = c&63;
        int row = ib*16 + (l&15);
        int kk  = k0 + (l>>4)*8;
        gl_lds16(hsb + base + (size_t)(s0+row)*HH + kk, Ah + c*8);
        gl_lds16(hsl + base + (size_t)(s0+row)*HH + kk, Al + c*8);
        gl_lds16(hsb + base + (size_t)(t0+row)*HH + kk, Bh + c*8);
        gl_lds16(hsl + base + (size_t)(t0+row)*HH + kk, Bl + c*8);
      }
      __syncthreads();
      bf16x8 ah[4], al[4], bh[4], bl[4];
      #pragma unroll
      for (int i=0;i<4;i++){
        ah[i] = *(const bf16x8*)&Ah[((wm*4+i)*64 + lane)*8];
        al[i] = *(const bf16x8*)&Al[((wm*4+i)*64 + lane)*8];
      }
      #pragma unroll
      for (int j=0;j<4;j++){
        bh[j] = *(const bf16x8*)&Bh[((wn*4+j)*64 + lane)*8];
        bl[j] = *(const bf16x8*)&Bl[((wn*4+j)*64 + lane)*8];
      }
      #pragma unroll
      for (int i=0;i<4;i++)
        #pragma unroll
        for (int j=0;j<4;j++){
          acc[i][j] = __builtin_amdgcn_mfma_f32_16x16x32_bf16(ah[i], bh[j], acc[i][j], 0, 0, 0);
          acc[i][j] = __builtin_amdgcn_mfma_f32_16x16x32_bf16(ah[i], bl[j], acc[i][j], 0, 0, 0);
          acc[i][j] = __builtin_amdgcn_mfma_f32_16x16x32_bf16(al[i], bh[j], acc[i][j], 0, 0, 0);
        }
    }
    #pragma unroll
    for (int i=0;i<4;i++){
      #pragma unroll
      for (int j=0;j<4;j++){
        int col = t0 + wn*64 + j*16 + lm;
        #pragma unroll
        for (int r4=0;r4<4;r4++){
          int row = s0 + wm*64 + i*16 + lq*4 + r4;
          sim[((size_t)(b*SS+row))*SS + col] = acc[i][j][r4];
        }
      }
    }
  }
}

// K-as: fused attention [0,2048) + simsm [2048,2304)
__global__ __launch_bounds__(256) void k_attn_simsm(const short* __restrict__ qbh, const short* __restrict__ kbh,
    const int* __restrict__ s1a, const int* __restrict__ s2a, float* __restrict__ uacc,
    const float* __restrict__ sim, float* __restrict__ v1g, float* __restrict__ v2g){
  __shared__ __align__(16) char smem[64000];
  int id = blockIdx.x, tid = threadIdx.x;
  int wave = tid>>6, lane = tid&63;
  if (id < 2048){
    int b = id&31, h = (id>>5)&7, zc = id>>8;
    int s1 = s1a[b], s2 = s2a[b];
    int qs = s1 + 1 + zc*64;
    if (qs >= s2) return;
    short* Ks = (short*)smem;
    short* Qs = Ks + 256*APAD;
    int lm = lane&15, lq = lane>>4;
    int jmax = (s1+15)>>4;
    int krows = jmax<<4;
    for (int i = tid; i < krows*12; i += 256){
      int r = i/12, c = i - r*12;
      *(int4*)&Ks[r*APAD + c*8] = *(const int4*)(kbh + ((size_t)(b*256+r))*HH + h*96 + c*8);
    }
    for (int i = tid; i < 64*12; i += 256){
      int r = i/12, c = i - r*12;
      int q = qs + r;
      int4 v = {0,0,0,0};
      if (q < SS) v = *(const int4*)(qbh + ((size_t)(b*SS+q))*HH + h*96 + c*8);
      *(int4*)&Qs[r*APAD + c*8] = v;
    }
    __syncthreads();
    f32x4 acc[16];
    #pragma unroll
    for (int j=0;j<16;j++) acc[j] = (f32x4){0.f,0.f,0.f,0.f};
    #pragma unroll
    for (int ks=0; ks<3; ks++){
      bf16x8 a = *(const bf16x8*)&Qs[(wave*16+lm)*APAD + ks*32 + lq*8];
      #pragma unroll
      for (int j=0;j<16;j++){
        if (j < jmax){
          bf16x8 bfr = *(const bf16x8*)&Ks[(j*16+lm)*APAD + ks*32 + lq*8];
          acc[j] = __builtin_amdgcn_mfma_f32_16x16x32_bf16(a, bfr, acc[j], 0, 0, 0);
        }
      }
    }
    const float scale = 0.1020620726f;
    float uj[16];
    #pragma unroll
    for (int j=0;j<16;j++) uj[j]=0.f;
    int qrow_base = qs + wave*16 + lq*4;
    #pragma unroll
    for (int r=0;r<4;r++){
      float m = -1e30f;
      float sc[16];
      #pragma unroll
      for (int j=0;j<16;j++){
        int c = j*16 + lm;
        float s = (c>=1 && c<s1) ? acc[j][r]*scale : -1e30f;
        sc[j] = s; m = fmaxf(m, s);
      }
      #pragma unroll
      for (int o=1;o<16;o<<=1) m = fmaxf(m, __shfl_xor(m, o));
      float ssum = 0.f;
      #pragma unroll
      for (int j=0;j<16;j++){ float p = expf(sc[j]-m); sc[j]=p; ssum += p; }
      #pragma unroll
      for (int o=1;o<16;o<<=1) ssum += __shfl_xor(ssum, o);
      bool rvalid = (qrow_base + r) < s2;
      float inv = rvalid ? 1.f/ssum : 0.f;
      #pragma unroll
      for (int j=0;j<16;j++) uj[j] += sc[j]*inv;
    }
    #pragma unroll
    for (int j=0;j<16;j++){
      if (j < jmax){
        float v = uj[j];
        v += __shfl_xor(v, 16);
        v += __shfl_xor(v, 32);
        if (lq==0 && v != 0.f)
          atomicAdd(&uacc[((size_t)(b*8+h))*256 + j*16 + lm], v);
      }
    }
  } else {
    int l = id - 2048;
    int b = l&31, cy = l>>5;
    int s1 = s1a[b], s2 = s2a[b];
    int r0 = cy*64;
    float* av = (float*)smem;
    for (int i=tid;i<2*4*SS;i+=256) av[i]=0.f;
    __syncthreads();
    for (int r = r0 + wave; r < r0+64; r += 4){
      int t0,t1,which;
      if (r>=1 && r<s1){ t0=s1+1; t1=s2; which=0; }
      else if (r>s1 && r<s2){ t0=1; t1=s1; which=1; }
      else continue;
      const float* row = sim + ((size_t)(b*SS+r))*SS;
      float vals[7]; float mx=-1e30f;
      #pragma unroll
      for (int j=0;j<7;j++){
        int t = t0 + lane + 64*j;
        vals[j] = (t<t1) ? row[t] : -1e30f;
        mx = fmaxf(mx, vals[j]);
      }
      mx = wred_max(mx);
      float ssum=0.f;
      #pragma unroll
      for (int j=0;j<7;j++){
        int t = t0+lane+64*j;
        vals[j] = (t<t1)? expf(vals[j]-mx) : 0.f;
        ssum += vals[j];
      }
      ssum = wred_sum(ssum);
      float inv = 1.f/ssum;
      #pragma unroll
      for (int j=0;j<7;j++){
        int t = t0+lane+64*j;
        if (t<t1) av[(which*4 + wave)*SS + t] += vals[j]*inv;
      }
    }
    __syncthreads();
    for (int t=tid;t<SS;t+=256){
      float a0 = av[0*SS+t]+av[1*SS+t]+av[2*SS+t]+av[3*SS+t];
      float a1 = av[4*SS+t]+av[5*SS+t]+av[6*SS+t]+av[7*SS+t];
      if (a0 != 0.f) atomicAdd(&v1g[b*SS+t], a0);
      if (a1 != 0.f) atomicAdd(&v2g[b*SS+t], a1);
    }
  }
}

// K-ca: fused ctx [0,192) + alvec [192,576)
__global__ __launch_bounds__(256) void k_ctx_alvec(const float* __restrict__ uacc, const float* __restrict__ vb,
    const int* __restrict__ s1a, const float* __restrict__ invnh, float* __restrict__ cmg,
    const float* __restrict__ hs, const float* __restrict__ v1g, const float* __restrict__ v2g,
    const float* __restrict__ invnp, float* __restrict__ catg){
  __shared__ __align__(16) char smem[9216];
  int id = blockIdx.x, tid = threadIdx.x;
  if (id < 192){
    int b = id&31, i0 = (id>>5)*128;
    int s1 = s1a[b]; int nk = s1-1;
    float inh = invnh[b];
    float* us = (float*)smem;
    float* ps = us + 2048;
    for (int idx=tid; idx<2048; idx+=256) us[idx] = uacc[(size_t)b*2048 + idx];
    __syncthreads();
    int ii = tid & 127, half = tid >> 7;
    int i = i0 + ii;
    int h = i/96;
    float a = 0.f;
    int lo = 1 + half*128;
    int hi = nk < (lo+127) ? nk : (lo+127);
    for (int sl=lo; sl<=hi; sl++)
      a += us[h*256+sl]*vb[((size_t)(b*256+sl))*HH + i];
    ps[half*128 + ii] = a;
    __syncthreads();
    if (tid < 128)
      cmg[(size_t)b*HH + i0 + tid] = (ps[tid] + ps[128+tid])*inh;
  } else {
    int l = id - 192;
    int b = l&31, d0 = (l>>5)*64;
    float* sv1 = (float*)smem;
    float* sv2 = sv1 + 512;
    float* p1  = sv2 + 512;
    float* p2  = p1 + 256;
    for (int t=tid;t<SS;t+=256){ sv1[t]=v1g[b*SS+t]; sv2[t]=v2g[b*SS+t]; }
    __syncthreads();
    int d = d0 + (tid&63), ch = tid>>6;
    float a1=0.f, a2=0.f;
    for (int t=ch*128; t<ch*128+128; t++){
      float x = hs[((size_t)(b*SS+t))*HH + d];
      a1 += sv1[t]*x; a2 += sv2[t]*x;
    }
    p1[ch*64 + (tid&63)]=a1; p2[ch*64 + (tid&63)]=a2;
    __syncthreads();
    if (tid < 64){
      float s1_ = p1[tid]+p1[64+tid]+p1[128+tid]+p1[192+tid];
      float s2_ = p2[tid]+p2[64+tid]+p2[128+tid]+p2[192+tid];
      catg[(size_t)b*1536 + d0 + tid]       = s1_*invnp[b];
      catg[(size_t)b*1536 + 768 + d0 + tid] = s2_*invnh[b];
    }
  }
}

// compile-time-K GEMV body (keeps unrolling / load pipelining)
template<int K>
__device__ __forceinline__ void gemv_ct(const float* __restrict__ x, const float* __restrict__ W,
    const float* __restrict__ bias, float* __restrict__ y, int b, int j0, int tid,
    float* xs, float* psum){
  for (int i=tid;i<K;i+=256) xs[i] = x[(size_t)b*K + i];
  __syncthreads();
  int jj = tid & 127, half = tid >> 7;
  int j = j0 + jj;
  float a = 0.f;
  #pragma unroll 8
  for (int i = half*(K/2); i < (half+1)*(K/2); i++)
    a += xs[i]*W[(size_t)i*HH + j];
  psum[half*128 + jj] = a;
  __syncthreads();
  if (tid < 128)
    y[(size_t)b*HH + j0 + tid] = bias[j0+tid] + psum[tid] + psum[128+tid];
}

// K-gB: fused wo-gemv [0,192) + al_w1-gemv [192,384); compile-time K paths
__global__ __launch_bounds__(256) void k_gemvB(const float* __restrict__ cmg, const float* __restrict__ wo,
    const float* __restrict__ bo, float* __restrict__ accg,
    const float* __restrict__ catg, const float* __restrict__ al_w1, const float* __restrict__ al_b1,
    float* __restrict__ tmpg){
  __shared__ float xs[1536];
  __shared__ float psum[256];
  int id = blockIdx.x, tid = threadIdx.x;
  if (id < 192){
    gemv_ct<768>(cmg, wo, bo, accg, id&31, (id>>5)*128, tid, xs, psum);
  } else {
    int l = id-192;
    gemv_ct<1536>(catg, al_w1, al_b1, tmpg, l&31, (l>>5)*128, tid, xs, psum);
  }
}

// K-tC: fused ap tail [0,32) + al tail [32,64) + feat2 [64,96) -> comb
__global__ __launch_bounds__(256) void k_tailsC(const float* __restrict__ accg, const float* __restrict__ apw,
    const float* __restrict__ apb, const float* __restrict__ tmpg, const float* __restrict__ al_w2,
    const float* __restrict__ al_b2, float* __restrict__ comb,
    const float* __restrict__ featd, const float* __restrict__ g, const float* __restrict__ be,
    const float* __restrict__ w2, const float* __restrict__ b2){
  __shared__ __align__(16) float smem[1664];
  int id = blockIdx.x, tid = threadIdx.x;
  if (id < 64){
    float* xs = smem;
    float* psum = smem + HH;
    const float *x, *W, *bias; int b, off;
    if (id < 32){ b = id; x=accg; W=apw; bias=apb; off=256; }
    else { b = id-32; x=tmpg; W=al_w2; bias=al_b2; off=384; }
    for (int i=tid;i<HH;i+=256) xs[i] = x[(size_t)b*HH + i];
    __syncthreads();
    int jj = tid & 127, half = tid >> 7;
    float a = 0.f;
    #pragma unroll 8
    for (int i = half*384; i < half*384+384; i++)
      a += xs[i]*W[(size_t)i*128 + jj];
    psum[half*128 + jj] = a;
    __syncthreads();
    if (tid < 128)
      comb[b*512 + off + tid] = telu_f(bias[tid] + psum[tid] + psum[128+tid]);
  } else {
    // feat2: LN + 512->128 + telu
    int b = id - 64;
    float* hv  = smem;          // 512
    float* hn  = hv + 512;      // 512
    float* red = hn + 512;      // 256
    float* ps  = red + 256;     // 256
    hv[tid] = featd[(size_t)b*512 + tid];
    hv[tid+256] = featd[(size_t)b*512 + tid + 256];
    __syncthreads();
    red[tid] = hv[tid] + hv[tid+256];
    __syncthreads();
    for (int st=128; st>0; st>>=1){ if (tid<st) red[tid]+=red[tid+st]; __syncthreads(); }
    float mean = red[0]*(1.f/512.f);
    __syncthreads();
    float d0 = hv[tid]-mean, d1 = hv[tid+256]-mean;
    red[tid] = d0*d0 + d1*d1;
    __syncthreads();
    for (int st=128; st>0; st>>=1){ if (tid<st) red[tid]+=red[tid+st]; __syncthreads(); }
    float inv = 1.f/sqrtf(red[0]*(1.f/512.f) + 1e-5f);
    __syncthreads();
    hn[tid]     = d0*inv*g[tid]     + be[tid];
    hn[tid+256] = d1*inv*g[tid+256] + be[tid+256];
    __syncthreads();
    int jj = tid & 127, half = tid >> 7;
    float a = 0.f;
    #pragma unroll 8
    for (int k = half*256; k < half*256+256; k++)
      a += hn[k]*w2[k*128 + jj];
    ps[half*128 + jj] = a;
    __syncthreads();
    if (tid < 128)
      comb[b*512 + tid] = telu_f(b2[tid] + ps[tid] + ps[128+tid]);
  }
}

// K10: classifier head
__global__ __launch_bounds__(64) void k_cls(const float* __restrict__ comb,
    const float* __restrict__ w1, const float* __restrict__ b1,
    const float* __restrict__ w2, const float* __restrict__ b2, float* __restrict__ out){
  int b=blockIdx.x, tid=threadIdx.x;
  __shared__ float cb[512];
  __shared__ float t1[64];
  for (int i=tid;i<512;i+=64) cb[i]=comb[b*512+i];
  __syncthreads();
  float a = b1[tid];
  for (int k=0;k<512;k++) a += cb[k]*w1[(size_t)k*64+tid];
  t1[tid]=telu_f(a);
  __syncthreads();
  if (tid<3){
    float o = b2[tid];
    for (int k=0;k<64;k++) o += t1[k]*w2[k*3+tid];
    out[b*3+tid]=o;
  }
}

extern "C" void kernel_launch(void* const* d_in, const int* in_sizes, int n_in,
                              void* d_out, int out_size, void* d_ws, size_t ws_size,
                              hipStream_t stream){
  const float* hs   = (const float*)d_in[0];
  const int*   ids  = (const int*)d_in[1];
  const int*   amask= (const int*)d_in[2];
  const float* fe_w1= (const float*)d_in[3];
  const float* fe_b1= (const float*)d_in[4];
  const float* fe_g = (const float*)d_in[5];
  const float* fe_be= (const float*)d_in[6];
  const float* fe_w2= (const float*)d_in[7];
  const float* fe_b2= (const float*)d_in[8];
  const float* al_w1= (const float*)d_in[9];
  const float* al_b1= (const float*)d_in[10];
  const float* al_w2= (const float*)d_in[11];
  const float* al_b2= (const float*)d_in[12];
  const float* wq   = (const float*)d_in[13];
  const float* bq   = (const float*)d_in[14];
  const float* wk   = (const float*)d_in[15];
  const float* bk   = (const float*)d_in[16];
  const float* wv   = (const float*)d_in[17];
  const float* bv   = (const float*)d_in[18];
  const float* wo   = (const float*)d_in[19];
  const float* bo   = (const float*)d_in[20];
  const float* dpw  = (const float*)d_in[21];
  const float* dpb  = (const float*)d_in[22];
  const float* apw  = (const float*)d_in[23];
  const float* apb  = (const float*)d_in[24];
  const float* clw1 = (const float*)d_in[25];
  const float* clb1 = (const float*)d_in[26];
  const float* clw2 = (const float*)d_in[27];
  const float* clb2 = (const float*)d_in[28];
  float* out = (float*)d_out;

  char* base = (char*)d_ws;
  size_t off = 0;
  auto alloc = [&](size_t bytes)->char*{ char* p = base + off; off += (bytes + 255) & ~(size_t)255; return p; };
  short* hsb  = (short*)alloc((size_t)32*SS*HH*2);
  short* hsl  = (short*)alloc((size_t)32*SS*HH*2);
  short* Wt   = (short*)alloc((size_t)3*HH*HH*2);
  short* qbh  = (short*)alloc((size_t)32*SS*HH*2);
  short* kbh  = (short*)alloc((size_t)32*256*HH*2);
  float* vb   = (float*)alloc((size_t)32*256*HH*4);
  float* simb = (float*)alloc((size_t)32*SS*SS*4);
  float* uacc = (float*)alloc((size_t)32*8*256*4);
  float* v1g  = (float*)alloc((size_t)32*SS*4);
  float* v2g  = (float*)alloc((size_t)32*SS*4);
  int*   s1a  = (int*)alloc(32*4);
  int*   s2a  = (int*)alloc(32*4);
  float* invnam=(float*)alloc(32*4);
  float* invnp =(float*)alloc(32*4);
  float* invnh =(float*)alloc(32*4);
  float* comb = (float*)alloc((size_t)32*512*4);
  float4* repp= (float4*)alloc((size_t)32*6*4*128*16);
  float* featd= (float*)alloc((size_t)32*512*4);
  float* catg = (float*)alloc((size_t)32*1536*4);
  float* tmpg = (float*)alloc((size_t)32*HH*4);
  float* cmg  = (float*)alloc((size_t)32*HH*4);
  float* accg = (float*)alloc((size_t)32*HH*4);

  k_scan<<<dim3(32), dim3(512), 0, stream>>>(ids, amask, s1a, s2a, invnam, invnp, invnh, uacc, v1g, v2g);
  k_g2<<<dim3(2496), dim3(256), 0, stream>>>(hs, amask, s1a, s2a, hsb, hsl, repp, wq, wk, wv, Wt);
  k_mm<<<dim3(2048), dim3(256), 0, stream>>>(hsb, hsl, Wt, bq, bk, bv, qbh, kbh, vb, s1a, s2a, simb);
  k_smallA<<<dim3(160), dim3(256), 0, stream>>>(repp, hs, invnam, invnp, invnh, fe_w1, fe_b1, featd, dpw, dpb, comb);
  k_attn_simsm<<<dim3(2304), dim3(256), 0, stream>>>(qbh, kbh, s1a, s2a, uacc, simb, v1g, v2g);
  k_ctx_alvec<<<dim3(576), dim3(256), 0, stream>>>(uacc, vb, s1a, invnh, cmg, hs, v1g, v2g, invnp, catg);
  k_gemvB<<<dim3(384), dim3(256), 0, stream>>>(cmg, wo, bo, accg, catg, al_w1, al_b1, tmpg);
  k_tailsC<<<dim3(96), dim3(256), 0, stream>>>(accg, apw, apb, tmpg, al_w2, al_b2, comb,
                                               featd, fe_g, fe_be, fe_w2, fe_b2);
  k_cls<<<dim3(32), dim3(64), 0, stream>>>(comb, clw1, clb1, clw2, clb2, out);
}

// Round 8
// 510.383 us; speedup vs baseline: 1.5071x; 1.0666x over previous
//
#include <hip/hip_runtime.h>
#include <hip/hip_bf16.h>
#include <math.h>

#define SS 512
#define HH 768
#define NEGV -1e9f
#define APAD 100

typedef float f32x4 __attribute__((ext_vector_type(4)));
typedef __bf16 bf16x8 __attribute__((ext_vector_type(8)));

__device__ __forceinline__ float telu_f(float x){ return x * tanhf(expf(x)); }

__device__ __forceinline__ short f2bf(float x){
  __hip_bfloat16 h = __float2bfloat16(x);
  return __builtin_bit_cast(short, h);
}
__device__ __forceinline__ float b2f(short s){
  __hip_bfloat16 h = __builtin_bit_cast(__hip_bfloat16, s);
  return __bfloat162float(h);
}

__device__ __forceinline__ void gl_lds16(const void* g, void* l){
  __builtin_amdgcn_global_load_lds((const __attribute__((address_space(1))) void*)g,
                                   (__attribute__((address_space(3))) void*)l, 16, 0, 0);
}

__device__ __forceinline__ float wred_max(float v){
  #pragma unroll
  for (int o=32;o>0;o>>=1) v = fmaxf(v, __shfl_xor(v, o));
  return v;
}
__device__ __forceinline__ float wred_sum(float v){
  #pragma unroll
  for (int o=32;o>0;o>>=1) v += __shfl_xor(v, o);
  return v;
}

// K0: per-batch SEP scan + mask counts + zero atomic accumulators
__global__ __launch_bounds__(512) void k_scan(const int* __restrict__ ids, const int* __restrict__ am,
                       int* s1a, int* s2a, float* invnam, float* invnp, float* invnh,
                       float* __restrict__ uacc, float* __restrict__ v1g, float* __restrict__ v2g){
  int b = blockIdx.x, tid = threadIdx.x;
  __shared__ int mn, mx, cnt;
  if (tid==0){ mn = 1<<30; mx = -1; cnt = 0; }
  __syncthreads();
  int id = ids[b*SS+tid];
  if (id==102){ atomicMin(&mn, tid); atomicMax(&mx, tid); }
  atomicAdd(&cnt, am[b*SS+tid]);
  #pragma unroll
  for (int i=0;i<4;i++) uacc[(size_t)b*2048 + tid + i*512] = 0.f;
  v1g[b*SS+tid] = 0.f;
  v2g[b*SS+tid] = 0.f;
  __syncthreads();
  if (tid==0){
    int s1 = mn; if (s1 > 255) s1 = 255; if (s1 < 1) s1 = 1;
    int s2 = mx; if (s2 < s1+1) s2 = s1+1; if (s2 > 511) s2 = 511;
    s1a[b]=s1; s2a[b]=s2;
    invnam[b] = 1.f/fmaxf((float)cnt, 1e-9f);
    invnp[b]  = 1.f/fmaxf((float)(s1-1), 1e-9f);
    invnh[b]  = 1.f/fmaxf((float)(s2-s1-1), 1e-9f);
  }
}

// K-g2: fused prep1 (hs->bf16 hi/lo + masked partial reductions) + wt (weight transpose).
__global__ __launch_bounds__(256) void k_g2(const float* __restrict__ hs, const int* __restrict__ amask,
    const int* __restrict__ s1a, const int* __restrict__ s2a,
    short* __restrict__ hsb, short* __restrict__ hsl, float4* __restrict__ repp,
    const float* __restrict__ wq, const float* __restrict__ wk, const float* __restrict__ wv,
    short* __restrict__ Wt){
  __shared__ __align__(16) char smem[16896];
  int id = blockIdx.x, tid = threadIdx.x;
  if (id < 768){
    int b = id&31, hc = (id>>5)%6, sc = id/192;
    int* ams = (int*)smem;
    float4* rb4 = (float4*)(smem + 512);
    int sbase = sc*128;
    if (tid < 128) ams[tid] = amask[b*SS + sbase + tid];
    __syncthreads();
    int s1 = s1a[b], s2 = s2a[b];
    int hlane = tid & 31, srow = tid >> 5;
    int h0 = hc*128 + hlane*4;
    float sm[4]={0,0,0,0}, sp[4]={0,0,0,0}, sh[4]={0,0,0,0};
    float mxv[4]={NEGV,NEGV,NEGV,NEGV};
    for (int si = srow; si < 128; si += 8){
      int s = sbase + si;
      float4 x = *(const float4*)(hs + ((size_t)(b*SS+s))*HH + h0);
      float xv[4] = {x.x,x.y,x.z,x.w};
      bool am = ams[si] > 0;
      bool ip = (s>=1 && s<s1), ih = (s>s1 && s<s2);
      short hi4[4], lo4[4];
      #pragma unroll
      for (int c=0;c<4;c++){
        if (am){ sm[c]+=xv[c]; mxv[c]=fmaxf(mxv[c],xv[c]); }
        if (ip) sp[c]+=xv[c];
        if (ih) sh[c]+=xv[c];
        hi4[c] = f2bf(xv[c]);
        lo4[c] = f2bf(xv[c] - b2f(hi4[c]));
      }
      *(short4*)(hsb + ((size_t)(b*SS+s))*HH + h0) = *(short4*)hi4;
      *(short4*)(hsl + ((size_t)(b*SS+s))*HH + h0) = *(short4*)lo4;
    }
    #pragma unroll
    for (int c=0;c<4;c++) rb4[srow*128 + hlane*4+c] = make_float4(sm[c], mxv[c], sp[c], sh[c]);
    __syncthreads();
    if (tid < 128){
      float4 a = rb4[tid];
      #pragma unroll
      for (int r=1;r<8;r++){
        float4 v = rb4[r*128 + tid];
        a.x += v.x; a.y = fmaxf(a.y, v.y); a.z += v.z; a.w += v.w;
      }
      repp[(((size_t)(b*6+hc))*4 + sc)*128 + tid] = a;
    }
  } else {
    int w = id - 768;
    int k0 = (w%24)*32, n0 = ((w/24)%24)*32, which = w/576;
    const float* W = which==0? wq : (which==1? wk : wv);
    float (*tl)[33] = (float(*)[33])smem;
    int r = tid>>3, c4 = (tid&7)*4;
    float4 v = *(const float4*)(W + (size_t)(k0+r)*HH + n0 + c4);
    tl[r][c4+0]=v.x; tl[r][c4+1]=v.y; tl[r][c4+2]=v.z; tl[r][c4+3]=v.w;
    __syncthreads();
    short4 o;
    o.x = f2bf(tl[c4+0][r]); o.y = f2bf(tl[c4+1][r]);
    o.z = f2bf(tl[c4+2][r]); o.w = f2bf(tl[c4+3][r]);
    *(short4*)(Wt + (size_t)which*HH*HH + (size_t)(n0+r)*HH + k0 + c4) = o;
  }
}

// helper: reconstruct xfe[b][h] or sdiff[b][h] into xs[0..767] from repp partials
__device__ __forceinline__ void build_vec(const float4* __restrict__ repp, const float* __restrict__ hs,
    const float* __restrict__ invnam, const float* __restrict__ invnp, const float* __restrict__ invnh,
    int b, int tid, bool want_sdiff, float* xs){
  for (int h = tid; h < HH; h += 256){
    int hc = h>>7, hr = h&127;
    float S=0.f, M=NEGV, P=0.f, Hh=0.f;
    #pragma unroll
    for (int sc=0; sc<4; sc++){
      float4 v = repp[(((size_t)(b*6+hc))*4 + sc)*128 + hr];
      S += v.x; M = fmaxf(M, v.y); P += v.z; Hh += v.w;
    }
    if (want_sdiff) xs[h] = fabsf(P*invnp[b] - Hh*invnh[b]);
    else            xs[h] = hs[((size_t)(b*SS))*HH + h] + S*invnam[b] + M;
  }
}

// K-mm: sim GEMM [0,512) + qkv GEMM [512,2048) + smallA [2048,2208)
// Both GEMM paths double-buffered via global_load_lds ping-pong.
__global__ __launch_bounds__(256) void k_mm(const short* __restrict__ hsb, const short* __restrict__ hsl,
    const short* __restrict__ Wt,
    const float* __restrict__ bq, const float* __restrict__ bk, const float* __restrict__ bv,
    short* __restrict__ qbh, short* __restrict__ kbh, float* __restrict__ vb,
    const int* __restrict__ s1a, const int* __restrict__ s2a, float* __restrict__ sim,
    const float4* __restrict__ repp, const float* __restrict__ hs,
    const float* __restrict__ invnam, const float* __restrict__ invnp, const float* __restrict__ invnh,
    const float* __restrict__ fe_w1, const float* __restrict__ fe_b1, float* __restrict__ featd,
    const float* __restrict__ dpw, const float* __restrict__ dpb, float* __restrict__ comb){
  __shared__ __align__(16) short smem_s[32768];   // 64 KB
  int id = blockIdx.x;
  int tid = threadIdx.x, lane = tid&63, wave = tid>>6;
  int wm = wave>>1, wn = wave&1;
  int lm = lane&15, lq = lane>>4;
  if (id < 512){
    // ---- sim (split-precision, dbuf 2x32KB) ----
    int local = id;
    int b = (local&7) + 8*(local>>7);     // XCD swizzle
    int t = (local>>3)&15;
    int s0 = (t>>2)*128, t0 = (t&3)*128;
    int s2 = s2a[b];
    if (s0 >= s2 || t0 >= s2) return;
    const size_t base = (size_t)b*SS*HH;
    auto stage = [&](int k0, int bufi){
      short* Ah = smem_s + bufi*16384;
      short* Al = Ah + 4096;
      short* Bh = Ah + 8192;
      short* Bl = Ah + 12288;
      #pragma unroll
      for (int t2=0;t2<2;t2++){
        int c = tid + t2*256;
        int ib = c>>6, l = c&63;
        int row = ib*16 + (l&15);
        int kk  = k0 + (l>>4)*8;
        gl_lds16(hsb + base + (size_t)(s0+row)*HH + kk, Ah + c*8);
        gl_lds16(hsl + base + (size_t)(s0+row)*HH + kk, Al + c*8);
        gl_lds16(hsb + base + (size_t)(t0+row)*HH + kk, Bh + c*8);
        gl_lds16(hsl + base + (size_t)(t0+row)*HH + kk, Bl + c*8);
      }
    };
    f32x4 acc[4][4];
    #pragma unroll
    for (int i=0;i<4;i++)
      #pragma unroll
      for (int j=0;j<4;j++) acc[i][j] = (f32x4){0.f,0.f,0.f,0.f};
    stage(0, 0);
    __syncthreads();
    int bufi = 0;
    for (int k0=0;k0<HH;k0+=32){
      if (k0+32 < HH) stage(k0+32, bufi^1);
      short* Ah = smem_s + bufi*16384;
      short* Al = Ah + 4096;
      short* Bh = Ah + 8192;
      short* Bl = Ah + 12288;
      bf16x8 ah[4], al[4], bh[4], bl[4];
      #pragma unroll
      for (int i=0;i<4;i++){
        ah[i] = *(const bf16x8*)&Ah[((wm*4+i)*64 + lane)*8];
        al[i] = *(const bf16x8*)&Al[((wm*4+i)*64 + lane)*8];
      }
      #pragma unroll
      for (int j=0;j<4;j++){
        bh[j] = *(const bf16x8*)&Bh[((wn*4+j)*64 + lane)*8];
        bl[j] = *(const bf16x8*)&Bl[((wn*4+j)*64 + lane)*8];
      }
      #pragma unroll
      for (int i=0;i<4;i++)
        #pragma unroll
        for (int j=0;j<4;j++){
          acc[i][j] = __builtin_amdgcn_mfma_f32_16x16x32_bf16(ah[i], bh[j], acc[i][j], 0, 0, 0);
          acc[i][j] = __builtin_amdgcn_mfma_f32_16x16x32_bf16(ah[i], bl[j], acc[i][j], 0, 0, 0);
          acc[i][j] = __builtin_amdgcn_mfma_f32_16x16x32_bf16(al[i], bh[j], acc[i][j], 0, 0, 0);
        }
      __syncthreads();
      bufi ^= 1;
    }
    #pragma unroll
    for (int i=0;i<4;i++){
      #pragma unroll
      for (int j=0;j<4;j++){
        int col = t0 + wn*64 + j*16 + lm;
        #pragma unroll
        for (int r4=0;r4<4;r4++){
          int row = s0 + wm*64 + i*16 + lq*4 + r4;
          sim[((size_t)(b*SS+row))*SS + col] = acc[i][j][r4];
        }
      }
    }
  } else if (id < 2048){
    // ---- qkv (dbuf 2x16KB) ----
    int which, local;
    int qid = id - 512;
    if (qid < 768){ which=0; local=qid; }
    else if (qid < 1152){ which=1; local=qid-768; }
    else { which=2; local=qid-1152; }
    int r8 = local & 7, n = (local>>3)%6, gq = local/48;
    int rt = gq*8 + r8;
    int n0 = n*128;
    int r0, b;
    if (which==0){ r0 = rt*128; b = r0>>9; }
    else { b = rt>>1; r0 = b*512 + (rt&1)*128; }
    int s1 = s1a[b], s2 = s2a[b];
    int s0 = r0 & (SS-1);
    if (which==0){ if (s0 >= s2 || s0 + 127 <= s1) return; }
    else { if (s0 >= s1) return; }
    const float* bias = which==0? bq : (which==1? bk : bv);
    const short* Wb = Wt + (size_t)which*HH*HH;
    auto stageq = [&](int k0, int bufi){
      short* As = smem_s + bufi*8192;
      short* Bs = As + 4096;
      #pragma unroll
      for (int t2=0;t2<2;t2++){
        int c = tid + t2*256;
        int ib = c>>6, l = c&63;
        int row = ib*16 + (l&15);
        int kk  = k0 + (l>>4)*8;
        gl_lds16(hsb + (size_t)(r0+row)*HH + kk, As + c*8);
        gl_lds16(Wb  + (size_t)(n0+row)*HH + kk, Bs + c*8);
      }
    };
    f32x4 acc[4][4];
    #pragma unroll
    for (int i=0;i<4;i++)
      #pragma unroll
      for (int j=0;j<4;j++) acc[i][j] = (f32x4){0.f,0.f,0.f,0.f};
    stageq(0, 0);
    __syncthreads();
    int bufi = 0;
    for (int k0=0;k0<HH;k0+=32){
      if (k0+32 < HH) stageq(k0+32, bufi^1);
      short* As = smem_s + bufi*8192;
      short* Bs = As + 4096;
      bf16x8 af[4], bfv[4];
      #pragma unroll
      for (int i=0;i<4;i++) af[i]  = *(const bf16x8*)&As[((wm*4+i)*64 + lane)*8];
      #pragma unroll
      for (int j=0;j<4;j++) bfv[j] = *(const bf16x8*)&Bs[((wn*4+j)*64 + lane)*8];
      #pragma unroll
      for (int i=0;i<4;i++)
        #pragma unroll
        for (int j=0;j<4;j++)
          acc[i][j] = __builtin_amdgcn_mfma_f32_16x16x32_bf16(af[i], bfv[j], acc[i][j], 0, 0, 0);
      __syncthreads();
      bufi ^= 1;
    }
    #pragma unroll
    for (int i=0;i<4;i++){
      #pragma unroll
      for (int j=0;j<4;j++){
        int col = n0 + wn*64 + j*16 + lm;
        float bcol = bias[col];
        #pragma unroll
        for (int r4=0;r4<4;r4++){
          int row = r0 + wm*64 + i*16 + lq*4 + r4;
          int s = row & (SS-1);
          float val = acc[i][j][r4] + bcol;
          if (which==0){
            if (s > s1 && s < s2) qbh[(size_t)row*HH + col] = f2bf(val);
          } else if (s >= 1 && s < s1){
            size_t o = ((size_t)(b*256+s))*HH + col;
            if (which==1) kbh[o] = f2bf(val); else vb[o] = val;
          }
        }
      }
    }
  } else {
    // ---- smallA: [2048,2176): gemv xfe@fe_w1 ; [2176,2208): diff tail ----
    int sid = id - 2048;
    float* xs = (float*)smem_s;         // 768 floats
    float* psum = xs + HH;              // 256 floats
    int jj = tid & 127, half = tid >> 7;
    if (sid < 128){
      int b = sid&31, j0 = (sid>>5)*128;
      build_vec(repp, hs, invnam, invnp, invnh, b, tid, false, xs);
      __syncthreads();
      float a = 0.f;
      #pragma unroll 8
      for (int i = half*384; i < half*384+384; i++)
        a += xs[i]*fe_w1[(size_t)i*512 + j0 + jj];
      psum[half*128 + jj] = a;
      __syncthreads();
      if (tid < 128)
        featd[(size_t)b*512 + j0 + tid] = fe_b1[j0+tid] + psum[tid] + psum[128+tid];
    } else {
      int b = sid - 128;
      build_vec(repp, hs, invnam, invnp, invnh, b, tid, true, xs);
      __syncthreads();
      float a = 0.f;
      #pragma unroll 8
      for (int i = half*384; i < half*384+384; i++)
        a += xs[i]*dpw[(size_t)i*128 + jj];
      psum[half*128 + jj] = a;
      __syncthreads();
      if (tid < 128)
        comb[b*512 + 128 + tid] = telu_f(dpb[tid] + psum[tid] + psum[128+tid]);
    }
  }
}

// K-as: fused attention [0,2048) + simsm [2048,2304)
__global__ __launch_bounds__(256) void k_attn_simsm(const short* __restrict__ qbh, const short* __restrict__ kbh,
    const int* __restrict__ s1a, const int* __restrict__ s2a, float* __restrict__ uacc,
    const float* __restrict__ sim, float* __restrict__ v1g, float* __restrict__ v2g){
  __shared__ __align__(16) char smem[64000];
  int id = blockIdx.x, tid = threadIdx.x;
  int wave = tid>>6, lane = tid&63;
  if (id < 2048){
    int b = id&31, h = (id>>5)&7, zc = id>>8;
    int s1 = s1a[b], s2 = s2a[b];
    int qs = s1 + 1 + zc*64;
    if (qs >= s2) return;
    short* Ks = (short*)smem;
    short* Qs = Ks + 256*APAD;
    int lm = lane&15, lq = lane>>4;
    int jmax = (s1+15)>>4;
    int krows = jmax<<4;
    for (int i = tid; i < krows*12; i += 256){
      int r = i/12, c = i - r*12;
      *(int4*)&Ks[r*APAD + c*8] = *(const int4*)(kbh + ((size_t)(b*256+r))*HH + h*96 + c*8);
    }
    for (int i = tid; i < 64*12; i += 256){
      int r = i/12, c = i - r*12;
      int q = qs + r;
      int4 v = {0,0,0,0};
      if (q < SS) v = *(const int4*)(qbh + ((size_t)(b*SS+q))*HH + h*96 + c*8);
      *(int4*)&Qs[r*APAD + c*8] = v;
    }
    __syncthreads();
    f32x4 acc[16];
    #pragma unroll
    for (int j=0;j<16;j++) acc[j] = (f32x4){0.f,0.f,0.f,0.f};
    #pragma unroll
    for (int ks=0; ks<3; ks++){
      bf16x8 a = *(const bf16x8*)&Qs[(wave*16+lm)*APAD + ks*32 + lq*8];
      #pragma unroll
      for (int j=0;j<16;j++){
        if (j < jmax){
          bf16x8 bfr = *(const bf16x8*)&Ks[(j*16+lm)*APAD + ks*32 + lq*8];
          acc[j] = __builtin_amdgcn_mfma_f32_16x16x32_bf16(a, bfr, acc[j], 0, 0, 0);
        }
      }
    }
    const float scale = 0.1020620726f;
    float uj[16];
    #pragma unroll
    for (int j=0;j<16;j++) uj[j]=0.f;
    int qrow_base = qs + wave*16 + lq*4;
    #pragma unroll
    for (int r=0;r<4;r++){
      float m = -1e30f;
      float sc[16];
      #pragma unroll
      for (int j=0;j<16;j++){
        int c = j*16 + lm;
        float s = (c>=1 && c<s1) ? acc[j][r]*scale : -1e30f;
        sc[j] = s; m = fmaxf(m, s);
      }
      #pragma unroll
      for (int o=1;o<16;o<<=1) m = fmaxf(m, __shfl_xor(m, o));
      float ssum = 0.f;
      #pragma unroll
      for (int j=0;j<16;j++){ float p = expf(sc[j]-m); sc[j]=p; ssum += p; }
      #pragma unroll
      for (int o=1;o<16;o<<=1) ssum += __shfl_xor(ssum, o);
      bool rvalid = (qrow_base + r) < s2;
      float inv = rvalid ? 1.f/ssum : 0.f;
      #pragma unroll
      for (int j=0;j<16;j++) uj[j] += sc[j]*inv;
    }
    #pragma unroll
    for (int j=0;j<16;j++){
      if (j < jmax){
        float v = uj[j];
        v += __shfl_xor(v, 16);
        v += __shfl_xor(v, 32);
        if (lq==0 && v != 0.f)
          atomicAdd(&uacc[((size_t)(b*8+h))*256 + j*16 + lm], v);
      }
    }
  } else {
    int l = id - 2048;
    int b = l&31, cy = l>>5;
    int s1 = s1a[b], s2 = s2a[b];
    int r0 = cy*64;
    float* av = (float*)smem;
    for (int i=tid;i<2*4*SS;i+=256) av[i]=0.f;
    __syncthreads();
    for (int r = r0 + wave; r < r0+64; r += 4){
      int t0,t1,which;
      if (r>=1 && r<s1){ t0=s1+1; t1=s2; which=0; }
      else if (r>s1 && r<s2){ t0=1; t1=s1; which=1; }
      else continue;
      const float* row = sim + ((size_t)(b*SS+r))*SS;
      float vals[7]; float mx=-1e30f;
      #pragma unroll
      for (int j=0;j<7;j++){
        int t = t0 + lane + 64*j;
        vals[j] = (t<t1) ? row[t] : -1e30f;
        mx = fmaxf(mx, vals[j]);
      }
      mx = wred_max(mx);
      float ssum=0.f;
      #pragma unroll
      for (int j=0;j<7;j++){
        int t = t0+lane+64*j;
        vals[j] = (t<t1)? expf(vals[j]-mx) : 0.f;
        ssum += vals[j];
      }
      ssum = wred_sum(ssum);
      float inv = 1.f/ssum;
      #pragma unroll
      for (int j=0;j<7;j++){
        int t = t0+lane+64*j;
        if (t<t1) av[(which*4 + wave)*SS + t] += vals[j]*inv;
      }
    }
    __syncthreads();
    for (int t=tid;t<SS;t+=256){
      float a0 = av[0*SS+t]+av[1*SS+t]+av[2*SS+t]+av[3*SS+t];
      float a1 = av[4*SS+t]+av[5*SS+t]+av[6*SS+t]+av[7*SS+t];
      if (a0 != 0.f) atomicAdd(&v1g[b*SS+t], a0);
      if (a1 != 0.f) atomicAdd(&v2g[b*SS+t], a1);
    }
  }
}

// K-ca: fused ctx [0,192) + alvec [192,576)
__global__ __launch_bounds__(256) void k_ctx_alvec(const float* __restrict__ uacc, const float* __restrict__ vb,
    const int* __restrict__ s1a, const float* __restrict__ invnh, float* __restrict__ cmg,
    const float* __restrict__ hs, const float* __restrict__ v1g, const float* __restrict__ v2g,
    const float* __restrict__ invnp, float* __restrict__ catg){
  __shared__ __align__(16) char smem[9216];
  int id = blockIdx.x, tid = threadIdx.x;
  if (id < 192){
    int b = id&31, i0 = (id>>5)*128;
    int s1 = s1a[b]; int nk = s1-1;
    float inh = invnh[b];
    float* us = (float*)smem;
    float* ps = us + 2048;
    for (int idx=tid; idx<2048; idx+=256) us[idx] = uacc[(size_t)b*2048 + idx];
    __syncthreads();
    int ii = tid & 127, half = tid >> 7;
    int i = i0 + ii;
    int h = i/96;
    float a = 0.f;
    int lo = 1 + half*128;
    int hi = nk < (lo+127) ? nk : (lo+127);
    for (int sl=lo; sl<=hi; sl++)
      a += us[h*256+sl]*vb[((size_t)(b*256+sl))*HH + i];
    ps[half*128 + ii] = a;
    __syncthreads();
    if (tid < 128)
      cmg[(size_t)b*HH + i0 + tid] = (ps[tid] + ps[128+tid])*inh;
  } else {
    int l = id - 192;
    int b = l&31, d0 = (l>>5)*64;
    float* sv1 = (float*)smem;
    float* sv2 = sv1 + 512;
    float* p1  = sv2 + 512;
    float* p2  = p1 + 256;
    for (int t=tid;t<SS;t+=256){ sv1[t]=v1g[b*SS+t]; sv2[t]=v2g[b*SS+t]; }
    __syncthreads();
    int d = d0 + (tid&63), ch = tid>>6;
    float a1=0.f, a2=0.f;
    for (int t=ch*128; t<ch*128+128; t++){
      float x = hs[((size_t)(b*SS+t))*HH + d];
      a1 += sv1[t]*x; a2 += sv2[t]*x;
    }
    p1[ch*64 + (tid&63)]=a1; p2[ch*64 + (tid&63)]=a2;
    __syncthreads();
    if (tid < 64){
      float s1_ = p1[tid]+p1[64+tid]+p1[128+tid]+p1[192+tid];
      float s2_ = p2[tid]+p2[64+tid]+p2[128+tid]+p2[192+tid];
      catg[(size_t)b*1536 + d0 + tid]       = s1_*invnp[b];
      catg[(size_t)b*1536 + 768 + d0 + tid] = s2_*invnh[b];
    }
  }
}

// compile-time-K GEMV body (keeps unrolling / load pipelining)
template<int K>
__device__ __forceinline__ void gemv_ct(const float* __restrict__ x, const float* __restrict__ W,
    const float* __restrict__ bias, float* __restrict__ y, int b, int j0, int tid,
    float* xs, float* psum){
  for (int i=tid;i<K;i+=256) xs[i] = x[(size_t)b*K + i];
  __syncthreads();
  int jj = tid & 127, half = tid >> 7;
  int j = j0 + jj;
  float a = 0.f;
  #pragma unroll 8
  for (int i = half*(K/2); i < (half+1)*(K/2); i++)
    a += xs[i]*W[(size_t)i*HH + j];
  psum[half*128 + jj] = a;
  __syncthreads();
  if (tid < 128)
    y[(size_t)b*HH + j0 + tid] = bias[j0+tid] + psum[tid] + psum[128+tid];
}

// K-gB: fused wo-gemv [0,192) + al_w1-gemv [192,384)
__global__ __launch_bounds__(256) void k_gemvB(const float* __restrict__ cmg, const float* __restrict__ wo,
    const float* __restrict__ bo, float* __restrict__ accg,
    const float* __restrict__ catg, const float* __restrict__ al_w1, const float* __restrict__ al_b1,
    float* __restrict__ tmpg){
  __shared__ float xs[1536];
  __shared__ float psum[256];
  int id = blockIdx.x, tid = threadIdx.x;
  if (id < 192){
    gemv_ct<768>(cmg, wo, bo, accg, id&31, (id>>5)*128, tid, xs, psum);
  } else {
    int l = id-192;
    gemv_ct<1536>(catg, al_w1, al_b1, tmpg, l&31, (l>>5)*128, tid, xs, psum);
  }
}

// K-tC: fused ap tail [0,32) + al tail [32,64) + feat2 [64,96) -> comb
__global__ __launch_bounds__(256) void k_tailsC(const float* __restrict__ accg, const float* __restrict__ apw,
    const float* __restrict__ apb, const float* __restrict__ tmpg, const float* __restrict__ al_w2,
    const float* __restrict__ al_b2, float* __restrict__ comb,
    const float* __restrict__ featd, const float* __restrict__ g, const float* __restrict__ be,
    const float* __restrict__ w2, const float* __restrict__ b2){
  __shared__ __align__(16) float smem[1664];
  int id = blockIdx.x, tid = threadIdx.x;
  if (id < 64){
    float* xs = smem;
    float* psum = smem + HH;
    const float *x, *W, *bias; int b, off;
    if (id < 32){ b = id; x=accg; W=apw; bias=apb; off=256; }
    else { b = id-32; x=tmpg; W=al_w2; bias=al_b2; off=384; }
    for (int i=tid;i<HH;i+=256) xs[i] = x[(size_t)b*HH + i];
    __syncthreads();
    int jj = tid & 127, half = tid >> 7;
    float a = 0.f;
    #pragma unroll 8
    for (int i = half*384; i < half*384+384; i++)
      a += xs[i]*W[(size_t)i*128 + jj];
    psum[half*128 + jj] = a;
    __syncthreads();
    if (tid < 128)
      comb[b*512 + off + tid] = telu_f(bias[tid] + psum[tid] + psum[128+tid]);
  } else {
    int b = id - 64;
    float* hv  = smem;
    float* hn  = hv + 512;
    float* red = hn + 512;
    float* ps  = red + 256;
    hv[tid] = featd[(size_t)b*512 + tid];
    hv[tid+256] = featd[(size_t)b*512 + tid + 256];
    __syncthreads();
    red[tid] = hv[tid] + hv[tid+256];
    __syncthreads();
    for (int st=128; st>0; st>>=1){ if (tid<st) red[tid]+=red[tid+st]; __syncthreads(); }
    float mean = red[0]*(1.f/512.f);
    __syncthreads();
    float d0 = hv[tid]-mean, d1 = hv[tid+256]-mean;
    red[tid] = d0*d0 + d1*d1;
    __syncthreads();
    for (int st=128; st>0; st>>=1){ if (tid<st) red[tid]+=red[tid+st]; __syncthreads(); }
    float inv = 1.f/sqrtf(red[0]*(1.f/512.f) + 1e-5f);
    __syncthreads();
    hn[tid]     = d0*inv*g[tid]     + be[tid];
    hn[tid+256] = d1*inv*g[tid+256] + be[tid+256];
    __syncthreads();
    int jj = tid & 127, half = tid >> 7;
    float a = 0.f;
    #pragma unroll 8
    for (int k = half*256; k < half*256+256; k++)
      a += hn[k]*w2[k*128 + jj];
    ps[half*128 + jj] = a;
    __syncthreads();
    if (tid < 128)
      comb[b*512 + tid] = telu_f(b2[tid] + ps[tid] + ps[128+tid]);
  }
}

// K10: classifier head
__global__ __launch_bounds__(64) void k_cls(const float* __restrict__ comb,
    const float* __restrict__ w1, const float* __restrict__ b1,
    const float* __restrict__ w2, const float* __restrict__ b2, float* __restrict__ out){
  int b=blockIdx.x, tid=threadIdx.x;
  __shared__ float cb[512];
  __shared__ float t1[64];
  for (int i=tid;i<512;i+=64) cb[i]=comb[b*512+i];
  __syncthreads();
  float a = b1[tid];
  for (int k=0;k<512;k++) a += cb[k]*w1[(size_t)k*64+tid];
  t1[tid]=telu_f(a);
  __syncthreads();
  if (tid<3){
    float o = b2[tid];
    for (int k=0;k<64;k++) o += t1[k]*w2[k*3+tid];
    out[b*3+tid]=o;
  }
}

extern "C" void kernel_launch(void* const* d_in, const int* in_sizes, int n_in,
                              void* d_out, int out_size, void* d_ws, size_t ws_size,
                              hipStream_t stream){
  const float* hs   = (const float*)d_in[0];
  const int*   ids  = (const int*)d_in[1];
  const int*   amask= (const int*)d_in[2];
  const float* fe_w1= (const float*)d_in[3];
  const float* fe_b1= (const float*)d_in[4];
  const float* fe_g = (const float*)d_in[5];
  const float* fe_be= (const float*)d_in[6];
  const float* fe_w2= (const float*)d_in[7];
  const float* fe_b2= (const float*)d_in[8];
  const float* al_w1= (const float*)d_in[9];
  const float* al_b1= (const float*)d_in[10];
  const float* al_w2= (const float*)d_in[11];
  const float* al_b2= (const float*)d_in[12];
  const float* wq   = (const float*)d_in[13];
  const float* bq   = (const float*)d_in[14];
  const float* wk   = (const float*)d_in[15];
  const float* bk   = (const float*)d_in[16];
  const float* wv   = (const float*)d_in[17];
  const float* bv   = (const float*)d_in[18];
  const float* wo   = (const float*)d_in[19];
  const float* bo   = (const float*)d_in[20];
  const float* dpw  = (const float*)d_in[21];
  const float* dpb  = (const float*)d_in[22];
  const float* apw  = (const float*)d_in[23];
  const float* apb  = (const float*)d_in[24];
  const float* clw1 = (const float*)d_in[25];
  const float* clb1 = (const float*)d_in[26];
  const float* clw2 = (const float*)d_in[27];
  const float* clb2 = (const float*)d_in[28];
  float* out = (float*)d_out;

  char* base = (char*)d_ws;
  size_t off = 0;
  auto alloc = [&](size_t bytes)->char*{ char* p = base + off; off += (bytes + 255) & ~(size_t)255; return p; };
  short* hsb  = (short*)alloc((size_t)32*SS*HH*2);
  short* hsl  = (short*)alloc((size_t)32*SS*HH*2);
  short* Wt   = (short*)alloc((size_t)3*HH*HH*2);
  short* qbh  = (short*)alloc((size_t)32*SS*HH*2);
  short* kbh  = (short*)alloc((size_t)32*256*HH*2);
  float* vb   = (float*)alloc((size_t)32*256*HH*4);
  float* simb = (float*)alloc((size_t)32*SS*SS*4);
  float* uacc = (float*)alloc((size_t)32*8*256*4);
  float* v1g  = (float*)alloc((size_t)32*SS*4);
  float* v2g  = (float*)alloc((size_t)32*SS*4);
  int*   s1a  = (int*)alloc(32*4);
  int*   s2a  = (int*)alloc(32*4);
  float* invnam=(float*)alloc(32*4);
  float* invnp =(float*)alloc(32*4);
  float* invnh =(float*)alloc(32*4);
  float* comb = (float*)alloc((size_t)32*512*4);
  float4* repp= (float4*)alloc((size_t)32*6*4*128*16);
  float* featd= (float*)alloc((size_t)32*512*4);
  float* catg = (float*)alloc((size_t)32*1536*4);
  float* tmpg = (float*)alloc((size_t)32*HH*4);
  float* cmg  = (float*)alloc((size_t)32*HH*4);
  float* accg = (float*)alloc((size_t)32*HH*4);

  k_scan<<<dim3(32), dim3(512), 0, stream>>>(ids, amask, s1a, s2a, invnam, invnp, invnh, uacc, v1g, v2g);
  k_g2<<<dim3(2496), dim3(256), 0, stream>>>(hs, amask, s1a, s2a, hsb, hsl, repp, wq, wk, wv, Wt);
  k_mm<<<dim3(2208), dim3(256), 0, stream>>>(hsb, hsl, Wt, bq, bk, bv, qbh, kbh, vb, s1a, s2a, simb,
                                             repp, hs, invnam, invnp, invnh, fe_w1, fe_b1, featd, dpw, dpb, comb);
  k_attn_simsm<<<dim3(2304), dim3(256), 0, stream>>>(qbh, kbh, s1a, s2a, uacc, simb, v1g, v2g);
  k_ctx_alvec<<<dim3(576), dim3(256), 0, stream>>>(uacc, vb, s1a, invnh, cmg, hs, v1g, v2g, invnp, catg);
  k_gemvB<<<dim3(384), dim3(256), 0, stream>>>(cmg, wo, bo, accg, catg, al_w1, al_b1, tmpg);
  k_tailsC<<<dim3(96), dim3(256), 0, stream>>>(accg, apw, apb, tmpg, al_w2, al_b2, comb,
                                               featd, fe_g, fe_be, fe_w2, fe_b2);
  k_cls<<<dim3(32), dim3(64), 0, stream>>>(comb, clw1, clb1, clw2, clb2, out);
}

// Round 9
// 478.468 us; speedup vs baseline: 1.6076x; 1.0667x over previous
//
#include <hip/hip_runtime.h>
#include <hip/hip_bf16.h>
#include <math.h>

#define SS 512
#define HH 768
#define NEGV -1e9f
#define APAD 100

typedef float f32x4 __attribute__((ext_vector_type(4)));
typedef __bf16 bf16x8 __attribute__((ext_vector_type(8)));

__device__ __forceinline__ float telu_f(float x){ return x * tanhf(expf(x)); }

__device__ __forceinline__ short f2bf(float x){
  __hip_bfloat16 h = __float2bfloat16(x);
  return __builtin_bit_cast(short, h);
}
__device__ __forceinline__ float b2f(short s){
  __hip_bfloat16 h = __builtin_bit_cast(__hip_bfloat16, s);
  return __bfloat162float(h);
}

__device__ __forceinline__ void gl_lds16(const void* g, void* l){
  __builtin_amdgcn_global_load_lds((const __attribute__((address_space(1))) void*)g,
                                   (__attribute__((address_space(3))) void*)l, 16, 0, 0);
}

__device__ __forceinline__ float wred_max(float v){
  #pragma unroll
  for (int o=32;o>0;o>>=1) v = fmaxf(v, __shfl_xor(v, o));
  return v;
}
__device__ __forceinline__ float wred_sum(float v){
  #pragma unroll
  for (int o=32;o>0;o>>=1) v += __shfl_xor(v, o);
  return v;
}

// K0: per-batch SEP scan + mask counts + zero atomic accumulators
__global__ __launch_bounds__(512) void k_scan(const int* __restrict__ ids, const int* __restrict__ am,
                       int* s1a, int* s2a, float* invnam, float* invnp, float* invnh,
                       float* __restrict__ uacc, float* __restrict__ v1g, float* __restrict__ v2g){
  int b = blockIdx.x, tid = threadIdx.x;
  __shared__ int mn, mx, cnt;
  if (tid==0){ mn = 1<<30; mx = -1; cnt = 0; }
  __syncthreads();
  int id = ids[b*SS+tid];
  if (id==102){ atomicMin(&mn, tid); atomicMax(&mx, tid); }
  atomicAdd(&cnt, am[b*SS+tid]);
  #pragma unroll
  for (int i=0;i<4;i++) uacc[(size_t)b*2048 + tid + i*512] = 0.f;
  v1g[b*SS+tid] = 0.f;
  v2g[b*SS+tid] = 0.f;
  __syncthreads();
  if (tid==0){
    int s1 = mn; if (s1 > 255) s1 = 255; if (s1 < 1) s1 = 1;
    int s2 = mx; if (s2 < s1+1) s2 = s1+1; if (s2 > 511) s2 = 511;
    s1a[b]=s1; s2a[b]=s2;
    invnam[b] = 1.f/fmaxf((float)cnt, 1e-9f);
    invnp[b]  = 1.f/fmaxf((float)(s1-1), 1e-9f);
    invnh[b]  = 1.f/fmaxf((float)(s2-s1-1), 1e-9f);
  }
}

// K-g2: fused prep1 (hs->bf16 hi/lo + masked partial reductions) + wt (weight transpose).
__global__ __launch_bounds__(256) void k_g2(const float* __restrict__ hs, const int* __restrict__ amask,
    const int* __restrict__ s1a, const int* __restrict__ s2a,
    short* __restrict__ hsb, short* __restrict__ hsl, float4* __restrict__ repp,
    const float* __restrict__ wq, const float* __restrict__ wk, const float* __restrict__ wv,
    short* __restrict__ Wt){
  __shared__ __align__(16) char smem[16896];
  int id = blockIdx.x, tid = threadIdx.x;
  if (id < 768){
    int b = id&31, hc = (id>>5)%6, sc = id/192;
    int* ams = (int*)smem;
    float4* rb4 = (float4*)(smem + 512);
    int sbase = sc*128;
    if (tid < 128) ams[tid] = amask[b*SS + sbase + tid];
    __syncthreads();
    int s1 = s1a[b], s2 = s2a[b];
    int hlane = tid & 31, srow = tid >> 5;
    int h0 = hc*128 + hlane*4;
    float sm[4]={0,0,0,0}, sp[4]={0,0,0,0}, sh[4]={0,0,0,0};
    float mxv[4]={NEGV,NEGV,NEGV,NEGV};
    for (int si = srow; si < 128; si += 8){
      int s = sbase + si;
      float4 x = *(const float4*)(hs + ((size_t)(b*SS+s))*HH + h0);
      float xv[4] = {x.x,x.y,x.z,x.w};
      bool am = ams[si] > 0;
      bool ip = (s>=1 && s<s1), ih = (s>s1 && s<s2);
      short hi4[4], lo4[4];
      #pragma unroll
      for (int c=0;c<4;c++){
        if (am){ sm[c]+=xv[c]; mxv[c]=fmaxf(mxv[c],xv[c]); }
        if (ip) sp[c]+=xv[c];
        if (ih) sh[c]+=xv[c];
        hi4[c] = f2bf(xv[c]);
        lo4[c] = f2bf(xv[c] - b2f(hi4[c]));
      }
      *(short4*)(hsb + ((size_t)(b*SS+s))*HH + h0) = *(short4*)hi4;
      *(short4*)(hsl + ((size_t)(b*SS+s))*HH + h0) = *(short4*)lo4;
    }
    #pragma unroll
    for (int c=0;c<4;c++) rb4[srow*128 + hlane*4+c] = make_float4(sm[c], mxv[c], sp[c], sh[c]);
    __syncthreads();
    if (tid < 128){
      float4 a = rb4[tid];
      #pragma unroll
      for (int r=1;r<8;r++){
        float4 v = rb4[r*128 + tid];
        a.x += v.x; a.y = fmaxf(a.y, v.y); a.z += v.z; a.w += v.w;
      }
      repp[(((size_t)(b*6+hc))*4 + sc)*128 + tid] = a;
    }
  } else {
    int w = id - 768;
    int k0 = (w%24)*32, n0 = ((w/24)%24)*32, which = w/576;
    const float* W = which==0? wq : (which==1? wk : wv);
    float (*tl)[33] = (float(*)[33])smem;
    int r = tid>>3, c4 = (tid&7)*4;
    float4 v = *(const float4*)(W + (size_t)(k0+r)*HH + n0 + c4);
    tl[r][c4+0]=v.x; tl[r][c4+1]=v.y; tl[r][c4+2]=v.z; tl[r][c4+3]=v.w;
    __syncthreads();
    short4 o;
    o.x = f2bf(tl[c4+0][r]); o.y = f2bf(tl[c4+1][r]);
    o.z = f2bf(tl[c4+2][r]); o.w = f2bf(tl[c4+3][r]);
    *(short4*)(Wt + (size_t)which*HH*HH + (size_t)(n0+r)*HH + k0 + c4) = o;
  }
}

// helper: reconstruct xfe[b][h] or sdiff[b][h] into xs[0..767] from repp partials
__device__ __forceinline__ void build_vec(const float4* __restrict__ repp, const float* __restrict__ hs,
    const float* __restrict__ invnam, const float* __restrict__ invnp, const float* __restrict__ invnh,
    int b, int tid, bool want_sdiff, float* xs){
  for (int h = tid; h < HH; h += 256){
    int hc = h>>7, hr = h&127;
    float S=0.f, M=NEGV, P=0.f, Hh=0.f;
    #pragma unroll
    for (int sc=0; sc<4; sc++){
      float4 v = repp[(((size_t)(b*6+hc))*4 + sc)*128 + hr];
      S += v.x; M = fmaxf(M, v.y); P += v.z; Hh += v.w;
    }
    if (want_sdiff) xs[h] = fabsf(P*invnp[b] - Hh*invnh[b]);
    else            xs[h] = hs[((size_t)(b*SS))*HH + h] + S*invnam[b] + M;
  }
}

// K-mm: sim upper-triangle GEMM [0,320) + qkv GEMM (BK=64) [320,1856) + smallA [1856,2016)
// 32 KB LDS everywhere -> 5 blocks/CU.
__global__ __launch_bounds__(256) void k_mm(const short* __restrict__ hsb, const short* __restrict__ hsl,
    const short* __restrict__ Wt,
    const float* __restrict__ bq, const float* __restrict__ bk, const float* __restrict__ bv,
    short* __restrict__ qbh, short* __restrict__ kbh, float* __restrict__ vb,
    const int* __restrict__ s1a, const int* __restrict__ s2a, float* __restrict__ sim,
    const float4* __restrict__ repp, const float* __restrict__ hs,
    const float* __restrict__ invnam, const float* __restrict__ invnp, const float* __restrict__ invnh,
    const float* __restrict__ fe_w1, const float* __restrict__ fe_b1, float* __restrict__ featd,
    const float* __restrict__ dpw, const float* __restrict__ dpb, float* __restrict__ comb){
  __shared__ __align__(16) short smem_s[16384];   // 32 KB
  int id = blockIdx.x;
  int tid = threadIdx.x, lane = tid&63, wave = tid>>6;
  int wm = wave>>1, wn = wave&1;
  int lm = lane&15, lq = lane>>4;
  if (id < 320){
    // ---- sim upper triangle (split-precision), diag tiles alias B:=A ----
    const int TI[10]={0,0,0,0,1,1,1,2,2,3};
    const int TJ[10]={0,1,2,3,1,2,3,2,3,3};
    int b8 = id & 7, q = id >> 3;
    int t = q % 10, bhi = q / 10;
    int b = b8 + 8*bhi;
    int s0 = TI[t]*128, t0 = TJ[t]*128;
    int s2 = s2a[b];
    if (t0 >= s2) return;    // ti<=tj so s0<=t0
    bool diag = (s0 == t0);
    short* Ah = smem_s;
    short* Al = Ah + 4096;
    short* Bh = diag ? Ah : (Ah + 8192);
    short* Bl = diag ? Al : (Ah + 12288);
    const size_t base = (size_t)b*SS*HH;
    f32x4 acc[4][4];
    #pragma unroll
    for (int i=0;i<4;i++)
      #pragma unroll
      for (int j=0;j<4;j++) acc[i][j] = (f32x4){0.f,0.f,0.f,0.f};
    for (int k0=0;k0<HH;k0+=32){
      __syncthreads();
      #pragma unroll
      for (int t2=0;t2<2;t2++){
        int c = tid + t2*256;
        int ib = c>>6, l = c&63;
        int row = ib*16 + (l&15);
        int kk  = k0 + (l>>4)*8;
        gl_lds16(hsb + base + (size_t)(s0+row)*HH + kk, Ah + c*8);
        gl_lds16(hsl + base + (size_t)(s0+row)*HH + kk, Al + c*8);
        if (!diag){
          gl_lds16(hsb + base + (size_t)(t0+row)*HH + kk, Bh + c*8);
          gl_lds16(hsl + base + (size_t)(t0+row)*HH + kk, Bl + c*8);
        }
      }
      __syncthreads();
      bf16x8 ah[4], al[4], bh[4], bl[4];
      #pragma unroll
      for (int i=0;i<4;i++){
        ah[i] = *(const bf16x8*)&Ah[((wm*4+i)*64 + lane)*8];
        al[i] = *(const bf16x8*)&Al[((wm*4+i)*64 + lane)*8];
      }
      #pragma unroll
      for (int j=0;j<4;j++){
        bh[j] = *(const bf16x8*)&Bh[((wn*4+j)*64 + lane)*8];
        bl[j] = *(const bf16x8*)&Bl[((wn*4+j)*64 + lane)*8];
      }
      #pragma unroll
      for (int i=0;i<4;i++)
        #pragma unroll
        for (int j=0;j<4;j++){
          acc[i][j] = __builtin_amdgcn_mfma_f32_16x16x32_bf16(ah[i], bh[j], acc[i][j], 0, 0, 0);
          acc[i][j] = __builtin_amdgcn_mfma_f32_16x16x32_bf16(ah[i], bl[j], acc[i][j], 0, 0, 0);
          acc[i][j] = __builtin_amdgcn_mfma_f32_16x16x32_bf16(al[i], bh[j], acc[i][j], 0, 0, 0);
        }
    }
    #pragma unroll
    for (int i=0;i<4;i++){
      #pragma unroll
      for (int j=0;j<4;j++){
        int col = t0 + wn*64 + j*16 + lm;
        #pragma unroll
        for (int r4=0;r4<4;r4++){
          int row = s0 + wm*64 + i*16 + lq*4 + r4;
          sim[((size_t)(b*SS+row))*SS + col] = acc[i][j][r4];
        }
      }
    }
    if (!diag){
      // mirror: sim[t][s] = sim[s][t]; rows r4 are consecutive -> float4 store
      #pragma unroll
      for (int i=0;i<4;i++){
        #pragma unroll
        for (int j=0;j<4;j++){
          int col  = t0 + wn*64 + j*16 + lm;
          int row0 = s0 + wm*64 + i*16 + lq*4;
          float4 v; v.x=acc[i][j][0]; v.y=acc[i][j][1]; v.z=acc[i][j][2]; v.w=acc[i][j][3];
          *(float4*)(sim + ((size_t)(b*SS+col))*SS + row0) = v;
        }
      }
    }
  } else if (id < 1856){
    // ---- qkv, BK=64: 32 MFMAs per barrier ----
    int which, local;
    int qid = id - 320;
    if (qid < 768){ which=0; local=qid; }
    else if (qid < 1152){ which=1; local=qid-768; }
    else { which=2; local=qid-1152; }
    int r8 = local & 7, n = (local>>3)%6, gq = local/48;
    int rt = gq*8 + r8;
    int n0 = n*128;
    int r0, b;
    if (which==0){ r0 = rt*128; b = r0>>9; }
    else { b = rt>>1; r0 = b*512 + (rt&1)*128; }
    int s1 = s1a[b], s2 = s2a[b];
    int s0 = r0 & (SS-1);
    if (which==0){ if (s0 >= s2 || s0 + 127 <= s1) return; }
    else { if (s0 >= s1) return; }
    const float* bias = which==0? bq : (which==1? bk : bv);
    const short* Wb = Wt + (size_t)which*HH*HH;
    short* As0 = smem_s;
    short* Bs0 = As0 + 4096;
    short* As1 = As0 + 8192;
    short* Bs1 = As0 + 12288;
    f32x4 acc[4][4];
    #pragma unroll
    for (int i=0;i<4;i++)
      #pragma unroll
      for (int j=0;j<4;j++) acc[i][j] = (f32x4){0.f,0.f,0.f,0.f};
    for (int k0=0;k0<HH;k0+=64){
      __syncthreads();
      #pragma unroll
      for (int t2=0;t2<2;t2++){
        int c = tid + t2*256;
        int ib = c>>6, l = c&63;
        int row = ib*16 + (l&15);
        int kk  = (l>>4)*8;
        gl_lds16(hsb + (size_t)(r0+row)*HH + k0 + kk,      As0 + c*8);
        gl_lds16(Wb  + (size_t)(n0+row)*HH + k0 + kk,      Bs0 + c*8);
        gl_lds16(hsb + (size_t)(r0+row)*HH + k0 + 32 + kk, As1 + c*8);
        gl_lds16(Wb  + (size_t)(n0+row)*HH + k0 + 32 + kk, Bs1 + c*8);
      }
      __syncthreads();
      bf16x8 af[4], bfv[4];
      #pragma unroll
      for (int i=0;i<4;i++) af[i]  = *(const bf16x8*)&As0[((wm*4+i)*64 + lane)*8];
      #pragma unroll
      for (int j=0;j<4;j++) bfv[j] = *(const bf16x8*)&Bs0[((wn*4+j)*64 + lane)*8];
      #pragma unroll
      for (int i=0;i<4;i++)
        #pragma unroll
        for (int j=0;j<4;j++)
          acc[i][j] = __builtin_amdgcn_mfma_f32_16x16x32_bf16(af[i], bfv[j], acc[i][j], 0, 0, 0);
      #pragma unroll
      for (int i=0;i<4;i++) af[i]  = *(const bf16x8*)&As1[((wm*4+i)*64 + lane)*8];
      #pragma unroll
      for (int j=0;j<4;j++) bfv[j] = *(const bf16x8*)&Bs1[((wn*4+j)*64 + lane)*8];
      #pragma unroll
      for (int i=0;i<4;i++)
        #pragma unroll
        for (int j=0;j<4;j++)
          acc[i][j] = __builtin_amdgcn_mfma_f32_16x16x32_bf16(af[i], bfv[j], acc[i][j], 0, 0, 0);
    }
    #pragma unroll
    for (int i=0;i<4;i++){
      #pragma unroll
      for (int j=0;j<4;j++){
        int col = n0 + wn*64 + j*16 + lm;
        float bcol = bias[col];
        #pragma unroll
        for (int r4=0;r4<4;r4++){
          int row = r0 + wm*64 + i*16 + lq*4 + r4;
          int s = row & (SS-1);
          float val = acc[i][j][r4] + bcol;
          if (which==0){
            if (s > s1 && s < s2) qbh[(size_t)row*HH + col] = f2bf(val);
          } else if (s >= 1 && s < s1){
            size_t o = ((size_t)(b*256+s))*HH + col;
            if (which==1) kbh[o] = f2bf(val); else vb[o] = val;
          }
        }
      }
    }
  } else {
    // ---- smallA: [1856,1984): gemv xfe@fe_w1 ; [1984,2016): diff tail ----
    int sid = id - 1856;
    float* xs = (float*)smem_s;
    float* psum = xs + HH;
    int jj = tid & 127, half = tid >> 7;
    if (sid < 128){
      int b = sid&31, j0 = (sid>>5)*128;
      build_vec(repp, hs, invnam, invnp, invnh, b, tid, false, xs);
      __syncthreads();
      float a = 0.f;
      #pragma unroll 8
      for (int i = half*384; i < half*384+384; i++)
        a += xs[i]*fe_w1[(size_t)i*512 + j0 + jj];
      psum[half*128 + jj] = a;
      __syncthreads();
      if (tid < 128)
        featd[(size_t)b*512 + j0 + tid] = fe_b1[j0+tid] + psum[tid] + psum[128+tid];
    } else {
      int b = sid - 128;
      build_vec(repp, hs, invnam, invnp, invnh, b, tid, true, xs);
      __syncthreads();
      float a = 0.f;
      #pragma unroll 8
      for (int i = half*384; i < half*384+384; i++)
        a += xs[i]*dpw[(size_t)i*128 + jj];
      psum[half*128 + jj] = a;
      __syncthreads();
      if (tid < 128)
        comb[b*512 + 128 + tid] = telu_f(dpb[tid] + psum[tid] + psum[128+tid]);
    }
  }
}

// K-as: fused attention [0,2048) + simsm [2048,2304)
__global__ __launch_bounds__(256) void k_attn_simsm(const short* __restrict__ qbh, const short* __restrict__ kbh,
    const int* __restrict__ s1a, const int* __restrict__ s2a, float* __restrict__ uacc,
    const float* __restrict__ sim, float* __restrict__ v1g, float* __restrict__ v2g){
  __shared__ __align__(16) char smem[64000];
  int id = blockIdx.x, tid = threadIdx.x;
  int wave = tid>>6, lane = tid&63;
  if (id < 2048){
    int b = id&31, h = (id>>5)&7, zc = id>>8;
    int s1 = s1a[b], s2 = s2a[b];
    int qs = s1 + 1 + zc*64;
    if (qs >= s2) return;
    short* Ks = (short*)smem;
    short* Qs = Ks + 256*APAD;
    int lm = lane&15, lq = lane>>4;
    int jmax = (s1+15)>>4;
    int krows = jmax<<4;
    for (int i = tid; i < krows*12; i += 256){
      int r = i/12, c = i - r*12;
      *(int4*)&Ks[r*APAD + c*8] = *(const int4*)(kbh + ((size_t)(b*256+r))*HH + h*96 + c*8);
    }
    for (int i = tid; i < 64*12; i += 256){
      int r = i/12, c = i - r*12;
      int q = qs + r;
      int4 v = {0,0,0,0};
      if (q < SS) v = *(const int4*)(qbh + ((size_t)(b*SS+q))*HH + h*96 + c*8);
      *(int4*)&Qs[r*APAD + c*8] = v;
    }
    __syncthreads();
    f32x4 acc[16];
    #pragma unroll
    for (int j=0;j<16;j++) acc[j] = (f32x4){0.f,0.f,0.f,0.f};
    #pragma unroll
    for (int ks=0; ks<3; ks++){
      bf16x8 a = *(const bf16x8*)&Qs[(wave*16+lm)*APAD + ks*32 + lq*8];
      #pragma unroll
      for (int j=0;j<16;j++){
        if (j < jmax){
          bf16x8 bfr = *(const bf16x8*)&Ks[(j*16+lm)*APAD + ks*32 + lq*8];
          acc[j] = __builtin_amdgcn_mfma_f32_16x16x32_bf16(a, bfr, acc[j], 0, 0, 0);
        }
      }
    }
    const float scale = 0.1020620726f;
    float uj[16];
    #pragma unroll
    for (int j=0;j<16;j++) uj[j]=0.f;
    int qrow_base = qs + wave*16 + lq*4;
    #pragma unroll
    for (int r=0;r<4;r++){
      float m = -1e30f;
      float sc[16];
      #pragma unroll
      for (int j=0;j<16;j++){
        int c = j*16 + lm;
        float s = (c>=1 && c<s1) ? acc[j][r]*scale : -1e30f;
        sc[j] = s; m = fmaxf(m, s);
      }
      #pragma unroll
      for (int o=1;o<16;o<<=1) m = fmaxf(m, __shfl_xor(m, o));
      float ssum = 0.f;
      #pragma unroll
      for (int j=0;j<16;j++){ float p = expf(sc[j]-m); sc[j]=p; ssum += p; }
      #pragma unroll
      for (int o=1;o<16;o<<=1) ssum += __shfl_xor(ssum, o);
      bool rvalid = (qrow_base + r) < s2;
      float inv = rvalid ? 1.f/ssum : 0.f;
      #pragma unroll
      for (int j=0;j<16;j++) uj[j] += sc[j]*inv;
    }
    #pragma unroll
    for (int j=0;j<16;j++){
      if (j < jmax){
        float v = uj[j];
        v += __shfl_xor(v, 16);
        v += __shfl_xor(v, 32);
        if (lq==0 && v != 0.f)
          atomicAdd(&uacc[((size_t)(b*8+h))*256 + j*16 + lm], v);
      }
    }
  } else {
    int l = id - 2048;
    int b = l&31, cy = l>>5;
    int s1 = s1a[b], s2 = s2a[b];
    int r0 = cy*64;
    float* av = (float*)smem;
    for (int i=tid;i<2*4*SS;i+=256) av[i]=0.f;
    __syncthreads();
    for (int r = r0 + wave; r < r0+64; r += 4){
      int t0,t1,which;
      if (r>=1 && r<s1){ t0=s1+1; t1=s2; which=0; }
      else if (r>s1 && r<s2){ t0=1; t1=s1; which=1; }
      else continue;
      const float* row = sim + ((size_t)(b*SS+r))*SS;
      float vals[7]; float mx=-1e30f;
      #pragma unroll
      for (int j=0;j<7;j++){
        int t = t0 + lane + 64*j;
        vals[j] = (t<t1) ? row[t] : -1e30f;
        mx = fmaxf(mx, vals[j]);
      }
      mx = wred_max(mx);
      float ssum=0.f;
      #pragma unroll
      for (int j=0;j<7;j++){
        int t = t0+lane+64*j;
        vals[j] = (t<t1)? expf(vals[j]-mx) : 0.f;
        ssum += vals[j];
      }
      ssum = wred_sum(ssum);
      float inv = 1.f/ssum;
      #pragma unroll
      for (int j=0;j<7;j++){
        int t = t0+lane+64*j;
        if (t<t1) av[(which*4 + wave)*SS + t] += vals[j]*inv;
      }
    }
    __syncthreads();
    for (int t=tid;t<SS;t+=256){
      float a0 = av[0*SS+t]+av[1*SS+t]+av[2*SS+t]+av[3*SS+t];
      float a1 = av[4*SS+t]+av[5*SS+t]+av[6*SS+t]+av[7*SS+t];
      if (a0 != 0.f) atomicAdd(&v1g[b*SS+t], a0);
      if (a1 != 0.f) atomicAdd(&v2g[b*SS+t], a1);
    }
  }
}

// K-ca: fused ctx [0,192) + alvec [192,576)
__global__ __launch_bounds__(256) void k_ctx_alvec(const float* __restrict__ uacc, const float* __restrict__ vb,
    const int* __restrict__ s1a, const float* __restrict__ invnh, float* __restrict__ cmg,
    const float* __restrict__ hs, const float* __restrict__ v1g, const float* __restrict__ v2g,
    const float* __restrict__ invnp, float* __restrict__ catg){
  __shared__ __align__(16) char smem[9216];
  int id = blockIdx.x, tid = threadIdx.x;
  if (id < 192){
    int b = id&31, i0 = (id>>5)*128;
    int s1 = s1a[b]; int nk = s1-1;
    float inh = invnh[b];
    float* us = (float*)smem;
    float* ps = us + 2048;
    for (int idx=tid; idx<2048; idx+=256) us[idx] = uacc[(size_t)b*2048 + idx];
    __syncthreads();
    int ii = tid & 127, half = tid >> 7;
    int i = i0 + ii;
    int h = i/96;
    float a = 0.f;
    int lo = 1 + half*128;
    int hi = nk < (lo+127) ? nk : (lo+127);
    for (int sl=lo; sl<=hi; sl++)
      a += us[h*256+sl]*vb[((size_t)(b*256+sl))*HH + i];
    ps[half*128 + ii] = a;
    __syncthreads();
    if (tid < 128)
      cmg[(size_t)b*HH + i0 + tid] = (ps[tid] + ps[128+tid])*inh;
  } else {
    int l = id - 192;
    int b = l&31, d0 = (l>>5)*64;
    float* sv1 = (float*)smem;
    float* sv2 = sv1 + 512;
    float* p1  = sv2 + 512;
    float* p2  = p1 + 256;
    for (int t=tid;t<SS;t+=256){ sv1[t]=v1g[b*SS+t]; sv2[t]=v2g[b*SS+t]; }
    __syncthreads();
    int d = d0 + (tid&63), ch = tid>>6;
    float a1=0.f, a2=0.f;
    for (int t=ch*128; t<ch*128+128; t++){
      float x = hs[((size_t)(b*SS+t))*HH + d];
      a1 += sv1[t]*x; a2 += sv2[t]*x;
    }
    p1[ch*64 + (tid&63)]=a1; p2[ch*64 + (tid&63)]=a2;
    __syncthreads();
    if (tid < 64){
      float s1_ = p1[tid]+p1[64+tid]+p1[128+tid]+p1[192+tid];
      float s2_ = p2[tid]+p2[64+tid]+p2[128+tid]+p2[192+tid];
      catg[(size_t)b*1536 + d0 + tid]       = s1_*invnp[b];
      catg[(size_t)b*1536 + 768 + d0 + tid] = s2_*invnh[b];
    }
  }
}

// compile-time-K GEMV body
template<int K>
__device__ __forceinline__ void gemv_ct(const float* __restrict__ x, const float* __restrict__ W,
    const float* __restrict__ bias, float* __restrict__ y, int b, int j0, int tid,
    float* xs, float* psum){
  for (int i=tid;i<K;i+=256) xs[i] = x[(size_t)b*K + i];
  __syncthreads();
  int jj = tid & 127, half = tid >> 7;
  int j = j0 + jj;
  float a = 0.f;
  #pragma unroll 8
  for (int i = half*(K/2); i < (half+1)*(K/2); i++)
    a += xs[i]*W[(size_t)i*HH + j];
  psum[half*128 + jj] = a;
  __syncthreads();
  if (tid < 128)
    y[(size_t)b*HH + j0 + tid] = bias[j0+tid] + psum[tid] + psum[128+tid];
}

// K-gB: fused wo-gemv [0,192) + al_w1-gemv [192,384)
__global__ __launch_bounds__(256) void k_gemvB(const float* __restrict__ cmg, const float* __restrict__ wo,
    const float* __restrict__ bo, float* __restrict__ accg,
    const float* __restrict__ catg, const float* __restrict__ al_w1, const float* __restrict__ al_b1,
    float* __restrict__ tmpg){
  __shared__ float xs[1536];
  __shared__ float psum[256];
  int id = blockIdx.x, tid = threadIdx.x;
  if (id < 192){
    gemv_ct<768>(cmg, wo, bo, accg, id&31, (id>>5)*128, tid, xs, psum);
  } else {
    int l = id-192;
    gemv_ct<1536>(catg, al_w1, al_b1, tmpg, l&31, (l>>5)*128, tid, xs, psum);
  }
}

// K-tC: fused ap tail [0,32) + al tail [32,64) + feat2 [64,96) -> comb
__global__ __launch_bounds__(256) void k_tailsC(const float* __restrict__ accg, const float* __restrict__ apw,
    const float* __restrict__ apb, const float* __restrict__ tmpg, const float* __restrict__ al_w2,
    const float* __restrict__ al_b2, float* __restrict__ comb,
    const float* __restrict__ featd, const float* __restrict__ g, const float* __restrict__ be,
    const float* __restrict__ w2, const float* __restrict__ b2){
  __shared__ __align__(16) float smem[1664];
  int id = blockIdx.x, tid = threadIdx.x;
  if (id < 64){
    float* xs = smem;
    float* psum = smem + HH;
    const float *x, *W, *bias; int b, off;
    if (id < 32){ b = id; x=accg; W=apw; bias=apb; off=256; }
    else { b = id-32; x=tmpg; W=al_w2; bias=al_b2; off=384; }
    for (int i=tid;i<HH;i+=256) xs[i] = x[(size_t)b*HH + i];
    __syncthreads();
    int jj = tid & 127, half = tid >> 7;
    float a = 0.f;
    #pragma unroll 8
    for (int i = half*384; i < half*384+384; i++)
      a += xs[i]*W[(size_t)i*128 + jj];
    psum[half*128 + jj] = a;
    __syncthreads();
    if (tid < 128)
      comb[b*512 + off + tid] = telu_f(bias[tid] + psum[tid] + psum[128+tid]);
  } else {
    int b = id - 64;
    float* hv  = smem;
    float* hn  = hv + 512;
    float* red = hn + 512;
    float* ps  = red + 256;
    hv[tid] = featd[(size_t)b*512 + tid];
    hv[tid+256] = featd[(size_t)b*512 + tid + 256];
    __syncthreads();
    red[tid] = hv[tid] + hv[tid+256];
    __syncthreads();
    for (int st=128; st>0; st>>=1){ if (tid<st) red[tid]+=red[tid+st]; __syncthreads(); }
    float mean = red[0]*(1.f/512.f);
    __syncthreads();
    float d0 = hv[tid]-mean, d1 = hv[tid+256]-mean;
    red[tid] = d0*d0 + d1*d1;
    __syncthreads();
    for (int st=128; st>0; st>>=1){ if (tid<st) red[tid]+=red[tid+st]; __syncthreads(); }
    float inv = 1.f/sqrtf(red[0]*(1.f/512.f) + 1e-5f);
    __syncthreads();
    hn[tid]     = d0*inv*g[tid]     + be[tid];
    hn[tid+256] = d1*inv*g[tid+256] + be[tid+256];
    __syncthreads();
    int jj = tid & 127, half = tid >> 7;
    float a = 0.f;
    #pragma unroll 8
    for (int k = half*256; k < half*256+256; k++)
      a += hn[k]*w2[k*128 + jj];
    ps[half*128 + jj] = a;
    __syncthreads();
    if (tid < 128)
      comb[b*512 + tid] = telu_f(b2[tid] + ps[tid] + ps[128+tid]);
  }
}

// K10: classifier head
__global__ __launch_bounds__(64) void k_cls(const float* __restrict__ comb,
    const float* __restrict__ w1, const float* __restrict__ b1,
    const float* __restrict__ w2, const float* __restrict__ b2, float* __restrict__ out){
  int b=blockIdx.x, tid=threadIdx.x;
  __shared__ float cb[512];
  __shared__ float t1[64];
  for (int i=tid;i<512;i+=64) cb[i]=comb[b*512+i];
  __syncthreads();
  float a = b1[tid];
  for (int k=0;k<512;k++) a += cb[k]*w1[(size_t)k*64+tid];
  t1[tid]=telu_f(a);
  __syncthreads();
  if (tid<3){
    float o = b2[tid];
    for (int k=0;k<64;k++) o += t1[k]*w2[k*3+tid];
    out[b*3+tid]=o;
  }
}

extern "C" void kernel_launch(void* const* d_in, const int* in_sizes, int n_in,
                              void* d_out, int out_size, void* d_ws, size_t ws_size,
                              hipStream_t stream){
  const float* hs   = (const float*)d_in[0];
  const int*   ids  = (const int*)d_in[1];
  const int*   amask= (const int*)d_in[2];
  const float* fe_w1= (const float*)d_in[3];
  const float* fe_b1= (const float*)d_in[4];
  const float* fe_g = (const float*)d_in[5];
  const float* fe_be= (const float*)d_in[6];
  const float* fe_w2= (const float*)d_in[7];
  const float* fe_b2= (const float*)d_in[8];
  const float* al_w1= (const float*)d_in[9];
  const float* al_b1= (const float*)d_in[10];
  const float* al_w2= (const float*)d_in[11];
  const float* al_b2= (const float*)d_in[12];
  const float* wq   = (const float*)d_in[13];
  const float* bq   = (const float*)d_in[14];
  const float* wk   = (const float*)d_in[15];
  const float* bk   = (const float*)d_in[16];
  const float* wv   = (const float*)d_in[17];
  const float* bv   = (const float*)d_in[18];
  const float* wo   = (const float*)d_in[19];
  const float* bo   = (const float*)d_in[20];
  const float* dpw  = (const float*)d_in[21];
  const float* dpb  = (const float*)d_in[22];
  const float* apw  = (const float*)d_in[23];
  const float* apb  = (const float*)d_in[24];
  const float* clw1 = (const float*)d_in[25];
  const float* clb1 = (const float*)d_in[26];
  const float* clw2 = (const float*)d_in[27];
  const float* clb2 = (const float*)d_in[28];
  float* out = (float*)d_out;

  char* base = (char*)d_ws;
  size_t off = 0;
  auto alloc = [&](size_t bytes)->char*{ char* p = base + off; off += (bytes + 255) & ~(size_t)255; return p; };
  short* hsb  = (short*)alloc((size_t)32*SS*HH*2);
  short* hsl  = (short*)alloc((size_t)32*SS*HH*2);
  short* Wt   = (short*)alloc((size_t)3*HH*HH*2);
  short* qbh  = (short*)alloc((size_t)32*SS*HH*2);
  short* kbh  = (short*)alloc((size_t)32*256*HH*2);
  float* vb   = (float*)alloc((size_t)32*256*HH*4);
  float* simb = (float*)alloc((size_t)32*SS*SS*4);
  float* uacc = (float*)alloc((size_t)32*8*256*4);
  float* v1g  = (float*)alloc((size_t)32*SS*4);
  float* v2g  = (float*)alloc((size_t)32*SS*4);
  int*   s1a  = (int*)alloc(32*4);
  int*   s2a  = (int*)alloc(32*4);
  float* invnam=(float*)alloc(32*4);
  float* invnp =(float*)alloc(32*4);
  float* invnh =(float*)alloc(32*4);
  float* comb = (float*)alloc((size_t)32*512*4);
  float4* repp= (float4*)alloc((size_t)32*6*4*128*16);
  float* featd= (float*)alloc((size_t)32*512*4);
  float* catg = (float*)alloc((size_t)32*1536*4);
  float* tmpg = (float*)alloc((size_t)32*HH*4);
  float* cmg  = (float*)alloc((size_t)32*HH*4);
  float* accg = (float*)alloc((size_t)32*HH*4);

  k_scan<<<dim3(32), dim3(512), 0, stream>>>(ids, amask, s1a, s2a, invnam, invnp, invnh, uacc, v1g, v2g);
  k_g2<<<dim3(2496), dim3(256), 0, stream>>>(hs, amask, s1a, s2a, hsb, hsl, repp, wq, wk, wv, Wt);
  k_mm<<<dim3(2016), dim3(256), 0, stream>>>(hsb, hsl, Wt, bq, bk, bv, qbh, kbh, vb, s1a, s2a, simb,
                                             repp, hs, invnam, invnp, invnh, fe_w1, fe_b1, featd, dpw, dpb, comb);
  k_attn_simsm<<<dim3(2304), dim3(256), 0, stream>>>(qbh, kbh, s1a, s2a, uacc, simb, v1g, v2g);
  k_ctx_alvec<<<dim3(576), dim3(256), 0, stream>>>(uacc, vb, s1a, invnh, cmg, hs, v1g, v2g, invnp, catg);
  k_gemvB<<<dim3(384), dim3(256), 0, stream>>>(cmg, wo, bo, accg, catg, al_w1, al_b1, tmpg);
  k_tailsC<<<dim3(96), dim3(256), 0, stream>>>(accg, apw, apb, tmpg, al_w2, al_b2, comb,
                                               featd, fe_g, fe_be, fe_w2, fe_b2);
  k_cls<<<dim3(32), dim3(64), 0, stream>>>(comb, clw1, clb1, clw2, clb2, out);
}